// Round 1
// baseline (2361.988 us; speedup 1.0000x reference)
//
#include <hip/hip_runtime.h>

typedef __attribute__((ext_vector_type(8))) short short8;
typedef __attribute__((ext_vector_type(4))) float floatx4;

__device__ __forceinline__ float b2f(short b) {
  union { unsigned u; float f; } v; v.u = ((unsigned)(unsigned short)b) << 16; return v.f;
}
__device__ __forceinline__ short f2b(float f) {
  union { float f; unsigned u; } v; v.f = f;
  return (short)((v.u + 0x7fffu + ((v.u >> 16) & 1u)) >> 16);
}
__device__ __forceinline__ float loadf(const void* p, size_t i, bool f32) {
  return f32 ? ((const float*)p)[i] : b2f(((const short*)p)[i]);
}
__device__ __forceinline__ short8 load8(const void* p, size_t i, bool f32) {
  if (f32) {
    const float* fp = (const float*)p + i;
    float4 a = *(const float4*)fp;
    float4 b = *(const float4*)(fp + 4);
    short8 r;
    r[0] = f2b(a.x); r[1] = f2b(a.y); r[2] = f2b(a.z); r[3] = f2b(a.w);
    r[4] = f2b(b.x); r[5] = f2b(b.y); r[6] = f2b(b.z); r[7] = f2b(b.w);
    return r;
  }
  return *(const short8*)((const short*)p + i);
}

// barrier that does NOT drain vmcnt: LDS visibility only, so register prefetch
// loads stay in flight across it (T14 async-stage; pattern verified in the
// 8-phase template). __syncthreads() would emit s_waitcnt vmcnt(0) and kill it.
#define BAR() do { asm volatile("s_waitcnt lgkmcnt(0)" ::: "memory"); \
                   __builtin_amdgcn_s_barrier(); } while (0)

// ---------- dtype detector: fp32 data read as shorts has random exponent fields
__global__ void detect_dtype(const unsigned short* __restrict__ w, int* __restrict__ flag) {
  __shared__ int cnt;
  if (threadIdx.x == 0) cnt = 0;
  __syncthreads();
  int bad = 0;
  for (int i = threadIdx.x; i < 4096; i += 256) {
    int e = (w[i] >> 7) & 0xFF;
    if (e >= 0xC8) bad++;  // |x| >= 2^73: impossible for real bf16 weights
  }
  atomicAdd(&cnt, bad);
  __syncthreads();
  if (threadIdx.x == 0) *flag = (cnt > 64) ? 1 : 0;
}

// ---------- GEMM: C[c_row0+M rows, N] = A[a_row0+.., K] @ B[K,N] (+bias)
// 128x128 tile, BK=32, 4 waves 2x2, 16x16x32 bf16 MFMA, fp32 acc.
// A/bias dtype: input-flag if aIn; B always input dtype; C fp32 iff (cOut && f32) else bf16.
__global__ __launch_bounds__(256, 2)
void gemm_bt(const void* __restrict__ A, int a_row0,
             const void* __restrict__ B, const void* __restrict__ bias,
             void* __restrict__ C, int c_row0, int N, int K,
             const int* __restrict__ dflag, int aIn, int cOut) {
  __shared__ short As[128 * 32];
  __shared__ short Bs[128 * 32];
  const bool f32 = (*dflag != 0);
  const bool a32 = aIn && f32;
  const bool c32 = cOut && f32;
  const int tid = threadIdx.x;
  const int lane = tid & 63, w = tid >> 6;
  const int wm = w & 1, wn = w >> 1;
  const int qg = lane >> 4, l16 = lane & 15;
  const int m0 = blockIdx.y << 7, n0 = blockIdx.x << 7;

  const int arow = tid >> 2, ak = (tid & 3) << 3;
  const int brow = tid >> 4, bc = (tid & 15) << 3;
  const int rot = tid & 15;

  floatx4 acc[4][4];
#pragma unroll
  for (int i = 0; i < 4; ++i)
#pragma unroll
    for (int j = 0; j < 4; ++j) acc[i][j] = (floatx4){0.f, 0.f, 0.f, 0.f};

  for (int k0 = 0; k0 < K; k0 += 32) {
    __syncthreads();
#pragma unroll
    for (int j = 0; j < 2; ++j) {
      short8 av = load8(A, (size_t)(a_row0 + m0 + j * 64 + arow) * K + (k0 + ak), a32);
      *(short8*)(As + (j * 64 + arow) * 32 + ak) = av;
      int kr = j * 16 + brow;  // tile-local k 0..31
      short8 bv = load8(B, (size_t)(k0 + kr) * N + (n0 + bc), f32);
      int kq = kr >> 3, kj = kr & 7;
#pragma unroll
      for (int s = 0; s < 8; ++s) {
        int u = (s + rot) & 7;  // rotate to spread banks
        int n = bc + u;
        Bs[(n << 5) + ((kq ^ (n & 3)) << 3) + kj] = bv[u];
      }
    }
    __syncthreads();
    short8 a[4];
#pragma unroll
    for (int mi = 0; mi < 4; ++mi)
      a[mi] = *(const short8*)(As + (wm * 64 + mi * 16 + l16) * 32 + qg * 8);
#pragma unroll
    for (int ni = 0; ni < 4; ++ni) {
      int n = wn * 64 + ni * 16 + l16;
      short8 b = *(const short8*)(Bs + (n << 5) + ((qg ^ (n & 3)) << 3));
#pragma unroll
      for (int mi = 0; mi < 4; ++mi)
        acc[mi][ni] = __builtin_amdgcn_mfma_f32_16x16x32_bf16(a[mi], b, acc[mi][ni], 0, 0, 0);
    }
  }
#pragma unroll
  for (int ni = 0; ni < 4; ++ni) {
    int col = n0 + wn * 64 + ni * 16 + l16;
    float bv = bias ? loadf(bias, col, f32) : 0.0f;
#pragma unroll
    for (int mi = 0; mi < 4; ++mi) {
      int row = m0 + wm * 64 + mi * 16 + qg * 4;
#pragma unroll
      for (int r = 0; r < 4; ++r) {
        size_t idx = (size_t)(c_row0 + row + r) * N + col;
        float val = acc[mi][ni][r] + bv;
        if (c32) ((float*)C)[idx] = val;
        else     ((short*)C)[idx] = f2b(val);
      }
    }
  }
}

// ---------- in-place RMSNorm + RoPE on q,k inside qkv[t][9216]; 1/sqrt(128) folded into q
__global__ __launch_bounds__(128)
void norm_rope(short* __restrict__ qkv, const int* __restrict__ ids,
               const void* __restrict__ nqw, const void* __restrict__ nkw,
               const void* __restrict__ naqw, const void* __restrict__ nakw,
               const int* __restrict__ dflag) {
  const bool f32 = (*dflag != 0);
  const int t = blockIdx.x, h = blockIdx.y, d = threadIdx.x;
  const size_t base = (size_t)t * 9216 + h * 128 + d;
  float qv = b2f(qkv[base]);
  float kv = b2f(qkv[base + 3072]);
  float sq = qv * qv, sk = kv * kv;
#pragma unroll
  for (int o = 1; o < 64; o <<= 1) { sq += __shfl_xor(sq, o); sk += __shfl_xor(sk, o); }
  __shared__ float red[2][2];
  if ((d & 63) == 0) { red[0][d >> 6] = sq; red[1][d >> 6] = sk; }
  __syncthreads();
  sq = red[0][0] + red[0][1];
  sk = red[1][0] + red[1][1];
  float rq = rsqrtf(sq * (1.0f / 128.0f) + 1e-5f);
  float rk = rsqrtf(sk * (1.0f / 128.0f) + 1e-5f);
  const bool txt = t < 512;
  float qn = qv * rq * loadf(txt ? naqw : nqw, d, f32);
  float kn = kv * rk * loadf(txt ? nakw : nkw, d, f32);
  // rope axes (16,56,56): 8 + 28 + 28 freq pairs
  int p = d >> 1, axis; float expo;
  if (p < 8)       { axis = 0; expo = (float)(2 * p) * (1.0f / 16.0f); }
  else if (p < 36) { axis = 1; expo = (float)(2 * (p - 8)) * (1.0f / 56.0f); }
  else             { axis = 2; expo = (float)(2 * (p - 36)) * (1.0f / 56.0f); }
  float freq = powf(10000.0f, -expo);
  float ang = (float)ids[t * 3 + axis] * freq;
  float s, c; sincosf(ang, &s, &c);
  float qp = __shfl_xor(qn, 1), kp = __shfl_xor(kn, 1);
  float sgn = (d & 1) ? 1.0f : -1.0f;
  float qo = qn * c + sgn * qp * s;
  float ko = kn * c + sgn * kp * s;
  qkv[base]        = f2b(qo * 0.08838834764831845f);
  qkv[base + 3072] = f2b(ko);
}

// ---------- flash attention over qkv[t][9216]: q at h*128, k at 3072+h*128, v at 6144+h*128.
// Q-tile 128, K-tile 128; 4 waves each own 32 q-rows (wave-private online softmax).
// QPs holds Q (hoisted to regs) then P; KVs holds K then V^T (transposed during staging).
//
// v2 changes:
//  - 1-D grid 480, XCD-grouped: blocks with wgid%8==c run on XCD c and cover heads
//    3c..3c+2. All 20 q-tile blocks of a head are co-resident on one XCD, so its
//    K/V stream (1.31 MB) stays L2-resident (3 heads ~= 3.9 MB of 4 MB L2).
//    Predicted FETCH_SIZE 721 MB -> <120 MB.
//  - K/V register prefetch one tile ahead (T14): loads issued right after the regs
//    are committed to LDS, consumed a full tile later. BAR() (lgkmcnt-only barrier)
//    keeps the loads in flight across barriers.
//  - Q loads / attn stores nontemporal: streamed-once data must not evict K/V from L2.
__global__ __launch_bounds__(256, 2)
void attn_fa(const short* __restrict__ qkv, short* __restrict__ attn) {
  __shared__ short QPs[128 * 128];
  __shared__ short KVs[128 * 128];
  const int wgid = blockIdx.x;
  const int xcd = wgid & 7, slot = wgid >> 3;
  const int h = xcd * 3 + slot / 20;
  const int qt = slot % 20;
  const int tid = threadIdx.x, lane = tid & 63, w = tid >> 6;
  const int qg = lane >> 4, l16 = lane & 15;
  const int q0 = qt << 7;
  const int srow = tid >> 4, sc = tid & 15;

  short8 kr[8], vr[8];
  {
    const short* Qg = qkv + (size_t)q0 * 9216 + h * 128;
    const short* Kg = qkv + 3072 + h * 128;
    const short* Vg = qkv + 6144 + h * 128;
    short8 qtmp[8];
#pragma unroll
    for (int j = 0; j < 8; ++j) {
      int row = j * 16 + srow;
      qtmp[j] = __builtin_nontemporal_load((const short8*)(Qg + (size_t)row * 9216 + sc * 8));
    }
    // prefetch K(0), V(0) — issued after Q loads so the Q-dependent wait leaves these in flight
#pragma unroll
    for (int j = 0; j < 8; ++j) {
      int row = j * 16 + srow;
      kr[j] = *(const short8*)(Kg + (size_t)row * 9216 + sc * 8);
      vr[j] = *(const short8*)(Vg + (size_t)row * 9216 + sc * 8);
    }
#pragma unroll
    for (int j = 0; j < 8; ++j) {
      int row = j * 16 + srow;
      *(short8*)(QPs + row * 128 + ((sc ^ (row & 7)) << 3)) = qtmp[j];
    }
  }
  BAR();
  short8 aq[2][4];
#pragma unroll
  for (int mi = 0; mi < 2; ++mi)
#pragma unroll
    for (int kc = 0; kc < 4; ++kc) {
      int row = w * 32 + mi * 16 + l16;
      aq[mi][kc] = *(const short8*)(QPs + row * 128 + (((kc * 4 + qg) ^ (row & 7)) << 3));
    }

  floatx4 acc_o[2][8];
#pragma unroll
  for (int mi = 0; mi < 2; ++mi)
#pragma unroll
    for (int nd = 0; nd < 8; ++nd) acc_o[mi][nd] = (floatx4){0.f, 0.f, 0.f, 0.f};
  float m_i[2][4], l_i[2][4];
#pragma unroll
  for (int mi = 0; mi < 2; ++mi)
#pragma unroll
    for (int r = 0; r < 4; ++r) { m_i[mi][r] = -1e30f; l_i[mi][r] = 0.0f; }

  for (int kt = 0; kt < 20; ++kt) {
    BAR();  // prev iteration's PV reads of KVs done
    // commit prefetched K regs -> LDS
#pragma unroll
    for (int j = 0; j < 8; ++j) {
      int row = j * 16 + srow;  // key token
      *(short8*)(KVs + row * 128 + ((sc ^ (row & 7)) << 3)) = kr[j];
    }
    // prefetch next tile's K (stays in flight across the barriers below)
    {
      int ktn = kt < 19 ? kt + 1 : 19;
      const short* Kg = qkv + (size_t)ktn * 128 * 9216 + 3072 + h * 128;
#pragma unroll
      for (int j = 0; j < 8; ++j) {
        int row = j * 16 + srow;
        kr[j] = *(const short8*)(Kg + (size_t)row * 9216 + sc * 8);
      }
    }
    BAR();
    floatx4 acc_s[2][8];
#pragma unroll
    for (int mi = 0; mi < 2; ++mi)
#pragma unroll
      for (int ni = 0; ni < 8; ++ni) acc_s[mi][ni] = (floatx4){0.f, 0.f, 0.f, 0.f};
#pragma unroll
    for (int kc = 0; kc < 4; ++kc) {
#pragma unroll
      for (int ni = 0; ni < 8; ++ni) {
        int row = ni * 16 + l16;  // key
        short8 b = *(const short8*)(KVs + row * 128 + (((kc * 4 + qg) ^ (row & 7)) << 3));
        acc_s[0][ni] = __builtin_amdgcn_mfma_f32_16x16x32_bf16(aq[0][kc], b, acc_s[0][ni], 0, 0, 0);
        acc_s[1][ni] = __builtin_amdgcn_mfma_f32_16x16x32_bf16(aq[1][kc], b, acc_s[1][ni], 0, 0, 0);
      }
    }
    float alpha[2][4];
#pragma unroll
    for (int mi = 0; mi < 2; ++mi) {
#pragma unroll
      for (int r = 0; r < 4; ++r) {
        float mx = acc_s[mi][0][r];
#pragma unroll
        for (int ni = 1; ni < 8; ++ni) mx = fmaxf(mx, acc_s[mi][ni][r]);
        mx = fmaxf(mx, __shfl_xor(mx, 1));
        mx = fmaxf(mx, __shfl_xor(mx, 2));
        mx = fmaxf(mx, __shfl_xor(mx, 4));
        mx = fmaxf(mx, __shfl_xor(mx, 8));
        float mn = fmaxf(m_i[mi][r], mx);
        alpha[mi][r] = __expf(m_i[mi][r] - mn);
        m_i[mi][r] = mn;
      }
    }
#pragma unroll
    for (int mi = 0; mi < 2; ++mi) {
      float rs[4] = {0.f, 0.f, 0.f, 0.f};
#pragma unroll
      for (int ni = 0; ni < 8; ++ni) {
#pragma unroll
        for (int r = 0; r < 4; ++r) {
          float pv = __expf(acc_s[mi][ni][r] - m_i[mi][r]);
          rs[r] += pv;
          int row = w * 32 + mi * 16 + qg * 4 + r;  // wave-private
          int col = ni * 16 + l16;
          QPs[row * 128 + (((col >> 3) ^ (row & 7)) << 3) + (col & 7)] = f2b(pv);
        }
      }
#pragma unroll
      for (int r = 0; r < 4; ++r) {
        float t = rs[r];
        t += __shfl_xor(t, 1); t += __shfl_xor(t, 2);
        t += __shfl_xor(t, 4); t += __shfl_xor(t, 8);
        l_i[mi][r] = alpha[mi][r] * l_i[mi][r] + t;
      }
#pragma unroll
      for (int nd = 0; nd < 8; ++nd)
#pragma unroll
        for (int r = 0; r < 4; ++r) acc_o[mi][nd][r] *= alpha[mi][r];
    }
    BAR();  // K reads done before V overwrites KVs
    // commit prefetched V regs -> LDS (transposed scatter)
#pragma unroll
    for (int j = 0; j < 8; ++j) {
      int r = j * 16 + srow;  // key token
#pragma unroll
      for (int s = 0; s < 8; ++s) {
        int u = (s + sc) & 7;  // rotate to spread banks
        int d = sc * 8 + u;
        KVs[d * 128 + (((r >> 3) ^ (d & 7)) << 3) + (r & 7)] = vr[j][u];
      }
    }
    // prefetch next tile's V
    {
      int ktn = kt < 19 ? kt + 1 : 19;
      const short* Vg = qkv + (size_t)ktn * 128 * 9216 + 6144 + h * 128;
#pragma unroll
      for (int j = 0; j < 8; ++j) {
        int row = j * 16 + srow;
        vr[j] = *(const short8*)(Vg + (size_t)row * 9216 + sc * 8);
      }
    }
    BAR();
#pragma unroll
    for (int kc = 0; kc < 4; ++kc) {
      int prow0 = w * 32 + l16;
      short8 ap0 = *(const short8*)(QPs + prow0 * 128 + (((kc * 4 + qg) ^ (prow0 & 7)) << 3));
      int prow1 = prow0 + 16;
      short8 ap1 = *(const short8*)(QPs + prow1 * 128 + (((kc * 4 + qg) ^ (prow1 & 7)) << 3));
#pragma unroll
      for (int nd = 0; nd < 8; ++nd) {
        int row = nd * 16 + l16;  // d index
        short8 b = *(const short8*)(KVs + row * 128 + (((kc * 4 + qg) ^ (row & 7)) << 3));
        acc_o[0][nd] = __builtin_amdgcn_mfma_f32_16x16x32_bf16(ap0, b, acc_o[0][nd], 0, 0, 0);
        acc_o[1][nd] = __builtin_amdgcn_mfma_f32_16x16x32_bf16(ap1, b, acc_o[1][nd], 0, 0, 0);
      }
    }
  }
#pragma unroll
  for (int mi = 0; mi < 2; ++mi) {
    float inv[4];
#pragma unroll
    for (int r = 0; r < 4; ++r) inv[r] = 1.0f / l_i[mi][r];
#pragma unroll
    for (int nd = 0; nd < 8; ++nd) {
#pragma unroll
      for (int r = 0; r < 4; ++r) {
        int row = q0 + w * 32 + mi * 16 + qg * 4 + r;
        int col = h * 128 + nd * 16 + l16;
        __builtin_nontemporal_store(f2b(acc_o[mi][nd][r] * inv[r]),
                                    attn + (size_t)row * 3072 + col);
      }
    }
  }
}

extern "C" void kernel_launch(void* const* d_in, const int* in_sizes, int n_in,
                              void* d_out, int out_size, void* d_ws, size_t ws_size,
                              hipStream_t stream) {
  (void)in_sizes; (void)n_in; (void)out_size; (void)ws_size;
  const void* hidden    = d_in[0];
  const void* enc       = d_in[1];
  const int*  ids       = (const int*)d_in[2];
  const void* w_qkv     = d_in[3];
  const void* w_add_qkv = d_in[4];
  const void* b_add_qkv = d_in[5];
  const void* w_out     = d_in[6];
  const void* b_out     = d_in[7];
  const void* w_add_out = d_in[8];
  const void* b_add_out = d_in[9];
  const void* nqw  = d_in[10];
  const void* nkw  = d_in[11];
  const void* naqw = d_in[12];
  const void* nakw = d_in[13];

  int*   dflag = (int*)d_ws;
  short* qkv   = (short*)((char*)d_ws + 256);   // [2560][9216] bf16
  short* attn  = qkv + (size_t)2560 * 9216;     // [2560][3072] bf16
  // total ws: 256 + 62,914,560 bytes ~= 60 MB

  detect_dtype<<<1, 256, 0, stream>>>((const unsigned short*)w_qkv, dflag);
  // QKV projections: enc rows 0..511 (with bias), img rows 512..2559
  gemm_bt<<<dim3(72, 4), 256, 0, stream>>>(enc, 0, w_add_qkv, b_add_qkv, qkv, 0, 9216, 3072, dflag, 1, 0);
  gemm_bt<<<dim3(72, 16), 256, 0, stream>>>(hidden, 0, w_qkv, nullptr, qkv, 512, 9216, 3072, dflag, 1, 0);
  // in-place norm + rope
  norm_rope<<<dim3(2560, 24), 128, 0, stream>>>(qkv, ids, nqw, nkw, naqw, nakw, dflag);
  // attention: 1-D grid, XCD-grouped head mapping (see kernel comment)
  attn_fa<<<dim3(480), 256, 0, stream>>>(qkv, attn);
  // output projections: img_out (rows 0..) then enc_out (at element 2048*3072)
  gemm_bt<<<dim3(24, 16), 256, 0, stream>>>(attn, 512, w_out, b_out, d_out, 0, 3072, 3072, dflag, 0, 1);
  gemm_bt<<<dim3(24, 4), 256, 0, stream>>>(attn, 0, w_add_out, b_add_out, d_out, 2048, 3072, 3072, dflag, 0, 1);
}

// Round 2
// 2196.146 us; speedup vs baseline: 1.0755x; 1.0755x over previous
//
#include <hip/hip_runtime.h>

typedef __attribute__((ext_vector_type(8))) short short8;
typedef __attribute__((ext_vector_type(4))) float floatx4;

__device__ __forceinline__ float b2f(short b) {
  union { unsigned u; float f; } v; v.u = ((unsigned)(unsigned short)b) << 16; return v.f;
}
__device__ __forceinline__ short f2b(float f) {
  union { float f; unsigned u; } v; v.f = f;
  return (short)((v.u + 0x7fffu + ((v.u >> 16) & 1u)) >> 16);
}
__device__ __forceinline__ float loadf(const void* p, size_t i, bool f32) {
  return f32 ? ((const float*)p)[i] : b2f(((const short*)p)[i]);
}
__device__ __forceinline__ short8 load8(const void* p, size_t i, bool f32) {
  if (f32) {
    const float* fp = (const float*)p + i;
    float4 a = *(const float4*)fp;
    float4 b = *(const float4*)(fp + 4);
    short8 r;
    r[0] = f2b(a.x); r[1] = f2b(a.y); r[2] = f2b(a.z); r[3] = f2b(a.w);
    r[4] = f2b(b.x); r[5] = f2b(b.y); r[6] = f2b(b.z); r[7] = f2b(b.w);
    return r;
  }
  return *(const short8*)((const short*)p + i);
}

// async global->LDS, 16B per lane. LDS dest = wave-uniform base + lane*16.
__device__ __forceinline__ void gload16(const short* g, short* l) {
  __builtin_amdgcn_global_load_lds(
      (const __attribute__((address_space(1))) unsigned int*)g,
      (__attribute__((address_space(3))) unsigned int*)l, 16, 0, 0);
}

// ---------- dtype detector: fp32 data read as shorts has random exponent fields
__global__ void detect_dtype(const unsigned short* __restrict__ w, int* __restrict__ flag) {
  __shared__ int cnt;
  if (threadIdx.x == 0) cnt = 0;
  __syncthreads();
  int bad = 0;
  for (int i = threadIdx.x; i < 4096; i += 256) {
    int e = (w[i] >> 7) & 0xFF;
    if (e >= 0xC8) bad++;  // |x| >= 2^73: impossible for real bf16 weights
  }
  atomicAdd(&cnt, bad);
  __syncthreads();
  if (threadIdx.x == 0) *flag = (cnt > 64) ? 1 : 0;
}

// ---------- GEMM: C[c_row0+M rows, N] = A[a_row0+.., K] @ B[K,N] (+bias)
// 128x128 tile, BK=32, 4 waves 2x2, 16x16x32 bf16 MFMA, fp32 acc.
__global__ __launch_bounds__(256, 2)
void gemm_bt(const void* __restrict__ A, int a_row0,
             const void* __restrict__ B, const void* __restrict__ bias,
             void* __restrict__ C, int c_row0, int N, int K,
             const int* __restrict__ dflag, int aIn, int cOut) {
  __shared__ short As[128 * 32];
  __shared__ short Bs[128 * 32];
  const bool f32 = (*dflag != 0);
  const bool a32 = aIn && f32;
  const bool c32 = cOut && f32;
  const int tid = threadIdx.x;
  const int lane = tid & 63, w = tid >> 6;
  const int wm = w & 1, wn = w >> 1;
  const int qg = lane >> 4, l16 = lane & 15;
  const int m0 = blockIdx.y << 7, n0 = blockIdx.x << 7;

  const int arow = tid >> 2, ak = (tid & 3) << 3;
  const int brow = tid >> 4, bc = (tid & 15) << 3;
  const int rot = tid & 15;

  floatx4 acc[4][4];
#pragma unroll
  for (int i = 0; i < 4; ++i)
#pragma unroll
    for (int j = 0; j < 4; ++j) acc[i][j] = (floatx4){0.f, 0.f, 0.f, 0.f};

  for (int k0 = 0; k0 < K; k0 += 32) {
    __syncthreads();
#pragma unroll
    for (int j = 0; j < 2; ++j) {
      short8 av = load8(A, (size_t)(a_row0 + m0 + j * 64 + arow) * K + (k0 + ak), a32);
      *(short8*)(As + (j * 64 + arow) * 32 + ak) = av;
      int kr = j * 16 + brow;  // tile-local k 0..31
      short8 bv = load8(B, (size_t)(k0 + kr) * N + (n0 + bc), f32);
      int kq = kr >> 3, kj = kr & 7;
#pragma unroll
      for (int s = 0; s < 8; ++s) {
        int u = (s + rot) & 7;  // rotate to spread banks
        int n = bc + u;
        Bs[(n << 5) + ((kq ^ (n & 3)) << 3) + kj] = bv[u];
      }
    }
    __syncthreads();
    short8 a[4];
#pragma unroll
    for (int mi = 0; mi < 4; ++mi)
      a[mi] = *(const short8*)(As + (wm * 64 + mi * 16 + l16) * 32 + qg * 8);
#pragma unroll
    for (int ni = 0; ni < 4; ++ni) {
      int n = wn * 64 + ni * 16 + l16;
      short8 b = *(const short8*)(Bs + (n << 5) + ((qg ^ (n & 3)) << 3));
#pragma unroll
      for (int mi = 0; mi < 4; ++mi)
        acc[mi][ni] = __builtin_amdgcn_mfma_f32_16x16x32_bf16(a[mi], b, acc[mi][ni], 0, 0, 0);
    }
  }
#pragma unroll
  for (int ni = 0; ni < 4; ++ni) {
    int col = n0 + wn * 64 + ni * 16 + l16;
    float bv = bias ? loadf(bias, col, f32) : 0.0f;
#pragma unroll
    for (int mi = 0; mi < 4; ++mi) {
      int row = m0 + wm * 64 + mi * 16 + qg * 4;
#pragma unroll
      for (int r = 0; r < 4; ++r) {
        size_t idx = (size_t)(c_row0 + row + r) * N + col;
        float val = acc[mi][ni][r] + bv;
        if (c32) ((float*)C)[idx] = val;
        else     ((short*)C)[idx] = f2b(val);
      }
    }
  }
}

// ---------- in-place RMSNorm + RoPE on q,k inside qkv[t][9216]; 1/sqrt(128) folded into q
__global__ __launch_bounds__(128)
void norm_rope(short* __restrict__ qkv, const int* __restrict__ ids,
               const void* __restrict__ nqw, const void* __restrict__ nkw,
               const void* __restrict__ naqw, const void* __restrict__ nakw,
               const int* __restrict__ dflag) {
  const bool f32 = (*dflag != 0);
  const int t = blockIdx.x, h = blockIdx.y, d = threadIdx.x;
  const size_t base = (size_t)t * 9216 + h * 128 + d;
  float qv = b2f(qkv[base]);
  float kv = b2f(qkv[base + 3072]);
  float sq = qv * qv, sk = kv * kv;
#pragma unroll
  for (int o = 1; o < 64; o <<= 1) { sq += __shfl_xor(sq, o); sk += __shfl_xor(sk, o); }
  __shared__ float red[2][2];
  if ((d & 63) == 0) { red[0][d >> 6] = sq; red[1][d >> 6] = sk; }
  __syncthreads();
  sq = red[0][0] + red[0][1];
  sk = red[1][0] + red[1][1];
  float rq = rsqrtf(sq * (1.0f / 128.0f) + 1e-5f);
  float rk = rsqrtf(sk * (1.0f / 128.0f) + 1e-5f);
  const bool txt = t < 512;
  float qn = qv * rq * loadf(txt ? naqw : nqw, d, f32);
  float kn = kv * rk * loadf(txt ? nakw : nkw, d, f32);
  // rope axes (16,56,56): 8 + 28 + 28 freq pairs
  int p = d >> 1, axis; float expo;
  if (p < 8)       { axis = 0; expo = (float)(2 * p) * (1.0f / 16.0f); }
  else if (p < 36) { axis = 1; expo = (float)(2 * (p - 8)) * (1.0f / 56.0f); }
  else             { axis = 2; expo = (float)(2 * (p - 36)) * (1.0f / 56.0f); }
  float freq = __expf(-expo * 9.210340371976184f);  // 10000^-expo
  float ang = (float)ids[t * 3 + axis] * freq;
  float s, c; sincosf(ang, &s, &c);
  float qp = __shfl_xor(qn, 1), kp = __shfl_xor(kn, 1);
  float sgn = (d & 1) ? 1.0f : -1.0f;
  float qo = qn * c + sgn * qp * s;
  float ko = kn * c + sgn * kp * s;
  qkv[base]        = f2b(qo * 0.08838834764831845f);
  qkv[base + 3072] = f2b(ko);
}

// ---------- flash attention v3.
// Q-tile 256, K-tile 128. 8 waves (512 thr), wave w owns q-rows [32w,32w+32).
// LDS: QPs 256x128 (Q staged then P), KVs[2] 128x128 each (K then V^T in same buf).
// K staged by global_load_lds with pre-swizzled per-lane SOURCE + linear dest
// (rule 21c), double-buffered: K(kt+1) issued right after top barrier, waited
// one iteration later with counted vmcnt(4). V prefetched to regs (vr[4], 32 VGPR)
// one iteration ahead; compiler's register-dep vmcnt does the counted wait.
// Barriers are lgkmcnt-only so async loads stay in flight across them.
__global__ __launch_bounds__(512, 2)
void attn_fa(const short* __restrict__ qkv, short* __restrict__ attn) {
  __shared__ short QPs[256 * 128];      // 64 KB
  __shared__ short KVs[2][128 * 128];   // 2 x 32 KB
  const int wgid = blockIdx.x;
  const int xcd = wgid & 7, slot = wgid >> 3;   // 30 slots/XCD
  const int h = xcd * 3 + slot / 10;            // 3 heads per XCD (L2-resident K/V)
  const int qt = slot % 10;
  const int tid = threadIdx.x, lane = tid & 63, w = tid >> 6;  // 8 waves
  const int qg = lane >> 4, l16 = lane & 15;
  const int lr = lane >> 4, lc = lane & 15;
  const int q0 = qt << 8;
  const int srow = tid >> 4, sc = tid & 15;

  const short* Qg  = qkv + (size_t)q0 * 9216 + h * 128;
  const short* Kg0 = qkv + 3072 + h * 128;
  const short* Vg0 = qkv + 6144 + h * 128;

  short8 vr[4];
  // ---- prologue: Q (8 gload/wave), K(0) (4 gload/wave), V(0) (4 reg loads/thr)
#pragma unroll
  for (int j = 0; j < 8; ++j) {
    int row = j * 32 + w * 4 + lr;
    gload16(Qg + (size_t)row * 9216 + ((lc ^ (row & 7)) << 3),
            QPs + (j * 32 + w * 4) * 128);
  }
#pragma unroll
  for (int j = 0; j < 4; ++j) {
    int row = j * 32 + w * 4 + lr;
    gload16(Kg0 + (size_t)row * 9216 + ((lc ^ (row & 7)) << 3),
            &KVs[0][(j * 32 + w * 4) * 128]);
  }
#pragma unroll
  for (int j = 0; j < 4; ++j) {
    int row = j * 32 + srow;
    vr[j] = *(const short8*)(Vg0 + (size_t)row * 9216 + sc * 8);
  }
  // wait Q only (K(0)+V(0) = 8 stay in flight), then read Q fragments
  asm volatile("s_waitcnt vmcnt(8) lgkmcnt(0)" ::: "memory");
  __builtin_amdgcn_s_barrier();
  short8 aq[2][4];
#pragma unroll
  for (int mi = 0; mi < 2; ++mi)
#pragma unroll
    for (int kc = 0; kc < 4; ++kc) {
      int row = w * 32 + mi * 16 + l16;
      aq[mi][kc] = *(const short8*)(QPs + row * 128 + (((kc * 4 + qg) ^ (row & 7)) << 3));
    }

  floatx4 acc_o[2][8];
#pragma unroll
  for (int mi = 0; mi < 2; ++mi)
#pragma unroll
    for (int nd = 0; nd < 8; ++nd) acc_o[mi][nd] = (floatx4){0.f, 0.f, 0.f, 0.f};
  float m_i[2][4], l_i[2][4];
#pragma unroll
  for (int mi = 0; mi < 2; ++mi)
#pragma unroll
    for (int r = 0; r < 4; ++r) { m_i[mi][r] = -1e30f; l_i[mi][r] = 0.0f; }

  for (int kt = 0; kt < 20; ++kt) {
    const int c = kt & 1;
    // in flight: K(kt)->KVs[c] (4, older), V(kt)->vr (4, newer).
    // Counted wait: K(kt)'s LDS writes done, V still in flight. All waves wait
    // their own K gloads BEFORE the barrier, so after it the full tile is valid.
    asm volatile("s_waitcnt vmcnt(4) lgkmcnt(0)" ::: "memory");
    __builtin_amdgcn_s_barrier();
    // issue K(kt+1) -> KVs[1-c] (buffer last read by PV(kt-1), drained above)
    if (kt < 19) {
      const short* Kg = qkv + ((size_t)(kt + 1) * 128) * 9216 + 3072 + h * 128;
#pragma unroll
      for (int j = 0; j < 4; ++j) {
        int row = j * 32 + w * 4 + lr;
        gload16(Kg + (size_t)row * 9216 + ((lc ^ (row & 7)) << 3),
                &KVs[1 - c][(j * 32 + w * 4) * 128]);
      }
    }
    // ---- QK^T from KVs[c]
    floatx4 acc_s[2][8];
#pragma unroll
    for (int mi = 0; mi < 2; ++mi)
#pragma unroll
      for (int ni = 0; ni < 8; ++ni) acc_s[mi][ni] = (floatx4){0.f, 0.f, 0.f, 0.f};
#pragma unroll
    for (int kc = 0; kc < 4; ++kc) {
#pragma unroll
      for (int ni = 0; ni < 8; ++ni) {
        int row = ni * 16 + l16;  // key
        short8 b = *(const short8*)(&KVs[c][row * 128 + (((kc * 4 + qg) ^ (row & 7)) << 3)]);
        acc_s[0][ni] = __builtin_amdgcn_mfma_f32_16x16x32_bf16(aq[0][kc], b, acc_s[0][ni], 0, 0, 0);
        acc_s[1][ni] = __builtin_amdgcn_mfma_f32_16x16x32_bf16(aq[1][kc], b, acc_s[1][ni], 0, 0, 0);
      }
    }
    // ---- online softmax (wave-private rows)
    float alpha[2][4];
#pragma unroll
    for (int mi = 0; mi < 2; ++mi) {
#pragma unroll
      for (int r = 0; r < 4; ++r) {
        float mx = acc_s[mi][0][r];
#pragma unroll
        for (int ni = 1; ni < 8; ++ni) mx = fmaxf(mx, acc_s[mi][ni][r]);
        mx = fmaxf(mx, __shfl_xor(mx, 1));
        mx = fmaxf(mx, __shfl_xor(mx, 2));
        mx = fmaxf(mx, __shfl_xor(mx, 4));
        mx = fmaxf(mx, __shfl_xor(mx, 8));
        float mn = fmaxf(m_i[mi][r], mx);
        alpha[mi][r] = __expf(m_i[mi][r] - mn);
        m_i[mi][r] = mn;
      }
    }
#pragma unroll
    for (int mi = 0; mi < 2; ++mi) {
      float rs[4] = {0.f, 0.f, 0.f, 0.f};
#pragma unroll
      for (int ni = 0; ni < 8; ++ni) {
#pragma unroll
        for (int r = 0; r < 4; ++r) {
          float pv = __expf(acc_s[mi][ni][r] - m_i[mi][r]);
          rs[r] += pv;
          int row = w * 32 + mi * 16 + qg * 4 + r;  // wave-private P rows
          int col = ni * 16 + l16;
          QPs[row * 128 + (((col >> 3) ^ (row & 7)) << 3) + (col & 7)] = f2b(pv);
        }
      }
#pragma unroll
      for (int r = 0; r < 4; ++r) {
        float t = rs[r];
        t += __shfl_xor(t, 1); t += __shfl_xor(t, 2);
        t += __shfl_xor(t, 4); t += __shfl_xor(t, 8);
        l_i[mi][r] = alpha[mi][r] * l_i[mi][r] + t;
      }
#pragma unroll
      for (int nd = 0; nd < 8; ++nd)
#pragma unroll
        for (int r = 0; r < 4; ++r) acc_o[mi][nd][r] *= alpha[mi][r];
    }
    // all QK^T reads of KVs[c] done before V^T overwrites it
    asm volatile("s_waitcnt lgkmcnt(0)" ::: "memory");
    __builtin_amdgcn_s_barrier();
    // commit V^T(kt) into KVs[c] (compiler inserts counted vmcnt for vr dep)
#pragma unroll
    for (int j = 0; j < 4; ++j) {
      int r = j * 32 + srow;  // key token
#pragma unroll
      for (int s = 0; s < 8; ++s) {
        int u = (s + sc) & 7;  // rotate to spread banks
        int d = sc * 8 + u;
        KVs[c][d * 128 + (((r >> 3) ^ (d & 7)) << 3) + (r & 7)] = vr[j][u];
      }
    }
    // issue V(kt+1) reg loads (in flight across PV + next QK^T)
    if (kt < 19) {
      const short* Vg = qkv + ((size_t)(kt + 1) * 128) * 9216 + 6144 + h * 128;
#pragma unroll
      for (int j = 0; j < 4; ++j) {
        int row = j * 32 + srow;
        vr[j] = *(const short8*)(Vg + (size_t)row * 9216 + sc * 8);
      }
    }
    asm volatile("s_waitcnt lgkmcnt(0)" ::: "memory");
    __builtin_amdgcn_s_barrier();
    // ---- PV from KVs[c] (V^T) and QPs (P, wave-private A rows)
#pragma unroll
    for (int kc = 0; kc < 4; ++kc) {
      int prow0 = w * 32 + l16;
      short8 ap0 = *(const short8*)(QPs + prow0 * 128 + (((kc * 4 + qg) ^ (prow0 & 7)) << 3));
      int prow1 = prow0 + 16;
      short8 ap1 = *(const short8*)(QPs + prow1 * 128 + (((kc * 4 + qg) ^ (prow1 & 7)) << 3));
#pragma unroll
      for (int nd = 0; nd < 8; ++nd) {
        int row = nd * 16 + l16;  // d index
        short8 b = *(const short8*)(&KVs[c][row * 128 + (((kc * 4 + qg) ^ (row & 7)) << 3)]);
        acc_o[0][nd] = __builtin_amdgcn_mfma_f32_16x16x32_bf16(ap0, b, acc_o[0][nd], 0, 0, 0);
        acc_o[1][nd] = __builtin_amdgcn_mfma_f32_16x16x32_bf16(ap1, b, acc_o[1][nd], 0, 0, 0);
      }
    }
  }
  // ---- epilogue
#pragma unroll
  for (int mi = 0; mi < 2; ++mi) {
    float inv[4];
#pragma unroll
    for (int r = 0; r < 4; ++r) inv[r] = 1.0f / l_i[mi][r];
#pragma unroll
    for (int nd = 0; nd < 8; ++nd) {
#pragma unroll
      for (int r = 0; r < 4; ++r) {
        int row = q0 + w * 32 + mi * 16 + qg * 4 + r;
        int col = h * 128 + nd * 16 + l16;
        attn[(size_t)row * 3072 + col] = f2b(acc_o[mi][nd][r] * inv[r]);
      }
    }
  }
}

extern "C" void kernel_launch(void* const* d_in, const int* in_sizes, int n_in,
                              void* d_out, int out_size, void* d_ws, size_t ws_size,
                              hipStream_t stream) {
  (void)in_sizes; (void)n_in; (void)out_size; (void)ws_size;
  const void* hidden    = d_in[0];
  const void* enc       = d_in[1];
  const int*  ids       = (const int*)d_in[2];
  const void* w_qkv     = d_in[3];
  const void* w_add_qkv = d_in[4];
  const void* b_add_qkv = d_in[5];
  const void* w_out     = d_in[6];
  const void* b_out     = d_in[7];
  const void* w_add_out = d_in[8];
  const void* b_add_out = d_in[9];
  const void* nqw  = d_in[10];
  const void* nkw  = d_in[11];
  const void* naqw = d_in[12];
  const void* nakw = d_in[13];

  int*   dflag = (int*)d_ws;
  short* qkv   = (short*)((char*)d_ws + 256);   // [2560][9216] bf16
  short* attn  = qkv + (size_t)2560 * 9216;     // [2560][3072] bf16
  // total ws: 256 + 62,914,560 bytes ~= 60 MB

  detect_dtype<<<1, 256, 0, stream>>>((const unsigned short*)w_qkv, dflag);
  // QKV projections: enc rows 0..511 (with bias), img rows 512..2559
  gemm_bt<<<dim3(72, 4), 256, 0, stream>>>(enc, 0, w_add_qkv, b_add_qkv, qkv, 0, 9216, 3072, dflag, 1, 0);
  gemm_bt<<<dim3(72, 16), 256, 0, stream>>>(hidden, 0, w_qkv, nullptr, qkv, 512, 9216, 3072, dflag, 1, 0);
  // in-place norm + rope
  norm_rope<<<dim3(2560, 24), 128, 0, stream>>>(qkv, ids, nqw, nkw, naqw, nakw, dflag);
  // attention: 240 blocks = 24 heads x 10 q-tiles of 256; XCD-grouped (3 heads/XCD)
  attn_fa<<<dim3(240), 512, 0, stream>>>(qkv, attn);
  // output projections: img_out (rows 0..) then enc_out (at element 2048*3072)
  gemm_bt<<<dim3(24, 16), 256, 0, stream>>>(attn, 512, w_out, b_out, d_out, 0, 3072, 3072, dflag, 0, 1);
  gemm_bt<<<dim3(24, 4), 256, 0, stream>>>(attn, 0, w_add_out, b_add_out, d_out, 2048, 3072, 3072, dflag, 0, 1);
}

// Round 3
// 1808.963 us; speedup vs baseline: 1.3057x; 1.2140x over previous
//
#include <hip/hip_runtime.h>

typedef __attribute__((ext_vector_type(8))) short short8;
typedef __attribute__((ext_vector_type(4))) float floatx4;

__device__ __forceinline__ float b2f(short b) {
  union { unsigned u; float f; } v; v.u = ((unsigned)(unsigned short)b) << 16; return v.f;
}
__device__ __forceinline__ short f2b(float f) {
  union { float f; unsigned u; } v; v.f = f;
  return (short)((v.u + 0x7fffu + ((v.u >> 16) & 1u)) >> 16);
}
__device__ __forceinline__ float loadf(const void* p, size_t i, bool f32) {
  return f32 ? ((const float*)p)[i] : b2f(((const short*)p)[i]);
}
__device__ __forceinline__ short8 load8(const void* p, size_t i, bool f32) {
  if (f32) {
    const float* fp = (const float*)p + i;
    float4 a = *(const float4*)fp;
    float4 b = *(const float4*)(fp + 4);
    short8 r;
    r[0] = f2b(a.x); r[1] = f2b(a.y); r[2] = f2b(a.z); r[3] = f2b(a.w);
    r[4] = f2b(b.x); r[5] = f2b(b.y); r[6] = f2b(b.z); r[7] = f2b(b.w);
    return r;
  }
  return *(const short8*)((const short*)p + i);
}

// async global->LDS, 16B per lane. LDS dest = wave-uniform base + lane*16.
__device__ __forceinline__ void gload16(const short* g, short* l) {
  __builtin_amdgcn_global_load_lds(
      (const __attribute__((address_space(1))) unsigned int*)g,
      (__attribute__((address_space(3))) unsigned int*)l, 16, 0, 0);
}

// ---------- dtype detector: fp32 data read as shorts has random exponent fields
__global__ void detect_dtype(const unsigned short* __restrict__ w, int* __restrict__ flag) {
  __shared__ int cnt;
  if (threadIdx.x == 0) cnt = 0;
  __syncthreads();
  int bad = 0;
  for (int i = threadIdx.x; i < 4096; i += 256) {
    int e = (w[i] >> 7) & 0xFF;
    if (e >= 0xC8) bad++;  // |x| >= 2^73: impossible for real bf16 weights
  }
  atomicAdd(&cnt, bad);
  __syncthreads();
  if (threadIdx.x == 0) *flag = (cnt > 64) ? 1 : 0;
}

// ---------- one-time dtype normalization: src (fp32 or bf16, per dflag) -> bf16
__global__ __launch_bounds__(256)
void cvt_bf16(const void* __restrict__ src, short* __restrict__ dst, long n8,
              const int* __restrict__ dflag) {
  const bool f32 = (*dflag != 0);
  long stride = (long)gridDim.x * 256;
  for (long i = (long)blockIdx.x * 256 + threadIdx.x; i < n8; i += stride) {
    long e = i * 8;
    if (f32) {
      const float* fp = (const float*)src + e;
      float4 a = *(const float4*)fp;
      float4 b = *(const float4*)(fp + 4);
      short8 r;
      r[0] = f2b(a.x); r[1] = f2b(a.y); r[2] = f2b(a.z); r[3] = f2b(a.w);
      r[4] = f2b(b.x); r[5] = f2b(b.y); r[6] = f2b(b.z); r[7] = f2b(b.w);
      *(short8*)(dst + e) = r;
    } else {
      *(short8*)(dst + e) = *(const short8*)((const short*)src + e);
    }
  }
}

// ---------- OLD GEMM (fallback when workspace too small for bf16 pool) ----------
__global__ __launch_bounds__(256, 2)
void gemm_bt(const void* __restrict__ A, int a_row0,
             const void* __restrict__ B, const void* __restrict__ bias,
             void* __restrict__ C, int c_row0, int N, int K,
             const int* __restrict__ dflag, int aIn, int cOut) {
  __shared__ short As[128 * 32];
  __shared__ short Bs[128 * 32];
  const bool f32 = (*dflag != 0);
  const bool a32 = aIn && f32;
  const bool c32 = cOut && f32;
  const int tid = threadIdx.x;
  const int lane = tid & 63, w = tid >> 6;
  const int wm = w & 1, wn = w >> 1;
  const int qg = lane >> 4, l16 = lane & 15;
  const int m0 = blockIdx.y << 7, n0 = blockIdx.x << 7;

  const int arow = tid >> 2, ak = (tid & 3) << 3;
  const int brow = tid >> 4, bc = (tid & 15) << 3;
  const int rot = tid & 15;

  floatx4 acc[4][4];
#pragma unroll
  for (int i = 0; i < 4; ++i)
#pragma unroll
    for (int j = 0; j < 4; ++j) acc[i][j] = (floatx4){0.f, 0.f, 0.f, 0.f};

  for (int k0 = 0; k0 < K; k0 += 32) {
    __syncthreads();
#pragma unroll
    for (int j = 0; j < 2; ++j) {
      short8 av = load8(A, (size_t)(a_row0 + m0 + j * 64 + arow) * K + (k0 + ak), a32);
      *(short8*)(As + (j * 64 + arow) * 32 + ak) = av;
      int kr = j * 16 + brow;
      short8 bv = load8(B, (size_t)(k0 + kr) * N + (n0 + bc), f32);
      int kq = kr >> 3, kj = kr & 7;
#pragma unroll
      for (int s = 0; s < 8; ++s) {
        int u = (s + rot) & 7;
        int n = bc + u;
        Bs[(n << 5) + ((kq ^ (n & 3)) << 3) + kj] = bv[u];
      }
    }
    __syncthreads();
    short8 a[4];
#pragma unroll
    for (int mi = 0; mi < 4; ++mi)
      a[mi] = *(const short8*)(As + (wm * 64 + mi * 16 + l16) * 32 + qg * 8);
#pragma unroll
    for (int ni = 0; ni < 4; ++ni) {
      int n = wn * 64 + ni * 16 + l16;
      short8 b = *(const short8*)(Bs + (n << 5) + ((qg ^ (n & 3)) << 3));
#pragma unroll
      for (int mi = 0; mi < 4; ++mi)
        acc[mi][ni] = __builtin_amdgcn_mfma_f32_16x16x32_bf16(a[mi], b, acc[mi][ni], 0, 0, 0);
    }
  }
#pragma unroll
  for (int ni = 0; ni < 4; ++ni) {
    int col = n0 + wn * 64 + ni * 16 + l16;
    float bv = bias ? loadf(bias, col, f32) : 0.0f;
#pragma unroll
    for (int mi = 0; mi < 4; ++mi) {
      int row = m0 + wm * 64 + mi * 16 + qg * 4;
#pragma unroll
      for (int r = 0; r < 4; ++r) {
        size_t idx = (size_t)(c_row0 + row + r) * N + col;
        float val = acc[mi][ni][r] + bv;
        if (c32) ((float*)C)[idx] = val;
        else     ((short*)C)[idx] = f2b(val);
      }
    }
  }
}

// ---------- NEW GEMM: pure-bf16 A/B, double-buffered, global_load_lds A staging.
// C[c_row0+.., N] = A[a_row0+.., K] @ B[K,N] (+bias from ORIGINAL ptr, dtype per dflag).
// 128x128 tile, BK=32, 4 waves 2x2, 16x16x32 bf16 MFMA, fp32 acc.
// A: LDS linear [row][4 chunks of 16B], source-swizzled chunk c -> c^(row&3)
//    (rule 21c: linear dest + inverse-swizzled source + swizzled read => 2-way free).
// B: reg-load short8 + transposing scatter into [n][k] (proven layout).
// Loads for tile t+1 issued BEFORE compute(t); one lgkm-only barrier per K-step.
__global__ __launch_bounds__(256, 2)
void gemm_bf(const short* __restrict__ A, int a_row0,
             const short* __restrict__ B, const void* __restrict__ bias,
             void* __restrict__ C, int c_row0, int N, int K,
             const int* __restrict__ dflag, int cOut) {
  __shared__ short As[2][128 * 32];
  __shared__ short Bs[2][128 * 32];
  const bool f32 = (*dflag != 0);
  const bool c32 = cOut && f32;
  const int tid = threadIdx.x;
  const int lane = tid & 63, w = tid >> 6;
  const int wm = w & 1, wn = w >> 1;
  const int qg = lane >> 4, l16 = lane & 15;
  const int m0 = blockIdx.y << 7, n0 = blockIdx.x << 7;
  const int brow = tid >> 4, bc = (tid & 15) << 3;
  const int rot = tid & 15;
  const int garow = lane >> 2;   // gload: row within 16-row group
  const int gcir = lane & 3;     // gload: 16B chunk within row
  const int nk = K >> 5;

  floatx4 acc[4][4];
#pragma unroll
  for (int i = 0; i < 4; ++i)
#pragma unroll
    for (int j = 0; j < 4; ++j) acc[i][j] = (floatx4){0.f, 0.f, 0.f, 0.f};

  short8 bv0, bv1;
  // ---- prologue: stage tile 0 into buffer 0
  {
#pragma unroll
    for (int j = 0; j < 2; ++j) {
      int row = w * 32 + j * 16 + garow;
      gload16(A + (size_t)(a_row0 + m0 + row) * K + ((gcir ^ (row & 3)) << 3),
              &As[0][(w * 2 + j) << 9]);
    }
    bv0 = *(const short8*)(B + (size_t)(0 + brow) * N + (n0 + bc));
    bv1 = *(const short8*)(B + (size_t)(16 + brow) * N + (n0 + bc));
    asm volatile("s_waitcnt vmcnt(0)" ::: "memory");
#pragma unroll
    for (int j = 0; j < 2; ++j) {
      short8 bv = j ? bv1 : bv0;
      int kr = j * 16 + brow, kq = kr >> 3, kj = kr & 7;
#pragma unroll
      for (int s = 0; s < 8; ++s) {
        int u = (s + rot) & 7;
        int n = bc + u;
        Bs[0][(n << 5) + ((kq ^ (n & 3)) << 3) + kj] = bv[u];
      }
    }
    asm volatile("s_waitcnt lgkmcnt(0)" ::: "memory");
    __builtin_amdgcn_s_barrier();
  }

  for (int t = 0; t < nk; ++t) {
    const int c = t & 1;
    // issue next tile's loads (overlap with compute below)
    if (t + 1 < nk) {
      const int k0 = (t + 1) << 5;
#pragma unroll
      for (int j = 0; j < 2; ++j) {
        int row = w * 32 + j * 16 + garow;
        gload16(A + (size_t)(a_row0 + m0 + row) * K + k0 + ((gcir ^ (row & 3)) << 3),
                &As[1 - c][(w * 2 + j) << 9]);
      }
      bv0 = *(const short8*)(B + (size_t)(k0 + brow) * N + (n0 + bc));
      bv1 = *(const short8*)(B + (size_t)(k0 + 16 + brow) * N + (n0 + bc));
    }
    // ---- compute tile t from As[c], Bs[c]
    short8 a[4];
#pragma unroll
    for (int mi = 0; mi < 4; ++mi) {
      int ra = wm * 64 + mi * 16 + l16;
      a[mi] = *(const short8*)(&As[c][(ra << 5) + ((qg ^ (ra & 3)) << 3)]);
    }
#pragma unroll
    for (int ni = 0; ni < 4; ++ni) {
      int n = wn * 64 + ni * 16 + l16;
      short8 b = *(const short8*)(&Bs[c][(n << 5) + ((qg ^ (n & 3)) << 3)]);
#pragma unroll
      for (int mi = 0; mi < 4; ++mi)
        acc[mi][ni] = __builtin_amdgcn_mfma_f32_16x16x32_bf16(a[mi], b, acc[mi][ni], 0, 0, 0);
    }
    // ---- commit tile t+1: wait own gloads+reg loads, scatter B, barrier
    if (t + 1 < nk) {
      asm volatile("s_waitcnt vmcnt(0)" ::: "memory");
#pragma unroll
      for (int j = 0; j < 2; ++j) {
        short8 bv = j ? bv1 : bv0;
        int kr = j * 16 + brow, kq = kr >> 3, kj = kr & 7;
#pragma unroll
        for (int s = 0; s < 8; ++s) {
          int u = (s + rot) & 7;
          int n = bc + u;
          Bs[1 - c][(n << 5) + ((kq ^ (n & 3)) << 3) + kj] = bv[u];
        }
      }
      asm volatile("s_waitcnt lgkmcnt(0)" ::: "memory");
      __builtin_amdgcn_s_barrier();
    }
  }
  // ---- epilogue
#pragma unroll
  for (int ni = 0; ni < 4; ++ni) {
    int col = n0 + wn * 64 + ni * 16 + l16;
    float bvv = bias ? loadf(bias, col, f32) : 0.0f;
#pragma unroll
    for (int mi = 0; mi < 4; ++mi) {
      int row = m0 + wm * 64 + mi * 16 + qg * 4;
#pragma unroll
      for (int r = 0; r < 4; ++r) {
        size_t idx = (size_t)(c_row0 + row + r) * N + col;
        float val = acc[mi][ni][r] + bvv;
        if (c32) ((float*)C)[idx] = val;
        else     ((short*)C)[idx] = f2b(val);
      }
    }
  }
}

// ---------- in-place RMSNorm + RoPE on q,k inside qkv[t][9216]; 1/sqrt(128) folded into q
__global__ __launch_bounds__(128)
void norm_rope(short* __restrict__ qkv, const int* __restrict__ ids,
               const void* __restrict__ nqw, const void* __restrict__ nkw,
               const void* __restrict__ naqw, const void* __restrict__ nakw,
               const int* __restrict__ dflag) {
  const bool f32 = (*dflag != 0);
  const int t = blockIdx.x, h = blockIdx.y, d = threadIdx.x;
  const size_t base = (size_t)t * 9216 + h * 128 + d;
  float qv = b2f(qkv[base]);
  float kv = b2f(qkv[base + 3072]);
  float sq = qv * qv, sk = kv * kv;
#pragma unroll
  for (int o = 1; o < 64; o <<= 1) { sq += __shfl_xor(sq, o); sk += __shfl_xor(sk, o); }
  __shared__ float red[2][2];
  if ((d & 63) == 0) { red[0][d >> 6] = sq; red[1][d >> 6] = sk; }
  __syncthreads();
  sq = red[0][0] + red[0][1];
  sk = red[1][0] + red[1][1];
  float rq = rsqrtf(sq * (1.0f / 128.0f) + 1e-5f);
  float rk = rsqrtf(sk * (1.0f / 128.0f) + 1e-5f);
  const bool txt = t < 512;
  float qn = qv * rq * loadf(txt ? naqw : nqw, d, f32);
  float kn = kv * rk * loadf(txt ? nakw : nkw, d, f32);
  // rope axes (16,56,56): 8 + 28 + 28 freq pairs
  int p = d >> 1, axis; float expo;
  if (p < 8)       { axis = 0; expo = (float)(2 * p) * (1.0f / 16.0f); }
  else if (p < 36) { axis = 1; expo = (float)(2 * (p - 8)) * (1.0f / 56.0f); }
  else             { axis = 2; expo = (float)(2 * (p - 36)) * (1.0f / 56.0f); }
  float freq = __expf(-expo * 9.210340371976184f);  // 10000^-expo
  float ang = (float)ids[t * 3 + axis] * freq;
  float s, c; sincosf(ang, &s, &c);
  float qp = __shfl_xor(qn, 1), kp = __shfl_xor(kn, 1);
  float sgn = (d & 1) ? 1.0f : -1.0f;
  float qo = qn * c + sgn * qp * s;
  float ko = kn * c + sgn * kp * s;
  qkv[base]        = f2b(qo * 0.08838834764831845f);
  qkv[base + 3072] = f2b(ko);
}

// ---------- flash attention (unchanged from R2).
// Q-tile 256, K-tile 128. 8 waves (512 thr), wave w owns q-rows [32w,32w+32).
__global__ __launch_bounds__(512, 2)
void attn_fa(const short* __restrict__ qkv, short* __restrict__ attn) {
  __shared__ short QPs[256 * 128];      // 64 KB
  __shared__ short KVs[2][128 * 128];   // 2 x 32 KB
  const int wgid = blockIdx.x;
  const int xcd = wgid & 7, slot = wgid >> 3;   // 30 slots/XCD
  const int h = xcd * 3 + slot / 10;            // 3 heads per XCD (L2-resident K/V)
  const int qt = slot % 10;
  const int tid = threadIdx.x, lane = tid & 63, w = tid >> 6;  // 8 waves
  const int qg = lane >> 4, l16 = lane & 15;
  const int lr = lane >> 4, lc = lane & 15;
  const int q0 = qt << 8;
  const int srow = tid >> 4, sc = tid & 15;

  const short* Qg  = qkv + (size_t)q0 * 9216 + h * 128;
  const short* Kg0 = qkv + 3072 + h * 128;
  const short* Vg0 = qkv + 6144 + h * 128;

  short8 vr[4];
#pragma unroll
  for (int j = 0; j < 8; ++j) {
    int row = j * 32 + w * 4 + lr;
    gload16(Qg + (size_t)row * 9216 + ((lc ^ (row & 7)) << 3),
            QPs + (j * 32 + w * 4) * 128);
  }
#pragma unroll
  for (int j = 0; j < 4; ++j) {
    int row = j * 32 + w * 4 + lr;
    gload16(Kg0 + (size_t)row * 9216 + ((lc ^ (row & 7)) << 3),
            &KVs[0][(j * 32 + w * 4) * 128]);
  }
#pragma unroll
  for (int j = 0; j < 4; ++j) {
    int row = j * 32 + srow;
    vr[j] = *(const short8*)(Vg0 + (size_t)row * 9216 + sc * 8);
  }
  asm volatile("s_waitcnt vmcnt(8) lgkmcnt(0)" ::: "memory");
  __builtin_amdgcn_s_barrier();
  short8 aq[2][4];
#pragma unroll
  for (int mi = 0; mi < 2; ++mi)
#pragma unroll
    for (int kc = 0; kc < 4; ++kc) {
      int row = w * 32 + mi * 16 + l16;
      aq[mi][kc] = *(const short8*)(QPs + row * 128 + (((kc * 4 + qg) ^ (row & 7)) << 3));
    }

  floatx4 acc_o[2][8];
#pragma unroll
  for (int mi = 0; mi < 2; ++mi)
#pragma unroll
    for (int nd = 0; nd < 8; ++nd) acc_o[mi][nd] = (floatx4){0.f, 0.f, 0.f, 0.f};
  float m_i[2][4], l_i[2][4];
#pragma unroll
  for (int mi = 0; mi < 2; ++mi)
#pragma unroll
    for (int r = 0; r < 4; ++r) { m_i[mi][r] = -1e30f; l_i[mi][r] = 0.0f; }

  for (int kt = 0; kt < 20; ++kt) {
    const int c = kt & 1;
    asm volatile("s_waitcnt vmcnt(4) lgkmcnt(0)" ::: "memory");
    __builtin_amdgcn_s_barrier();
    if (kt < 19) {
      const short* Kg = qkv + ((size_t)(kt + 1) * 128) * 9216 + 3072 + h * 128;
#pragma unroll
      for (int j = 0; j < 4; ++j) {
        int row = j * 32 + w * 4 + lr;
        gload16(Kg + (size_t)row * 9216 + ((lc ^ (row & 7)) << 3),
                &KVs[1 - c][(j * 32 + w * 4) * 128]);
      }
    }
    floatx4 acc_s[2][8];
#pragma unroll
    for (int mi = 0; mi < 2; ++mi)
#pragma unroll
      for (int ni = 0; ni < 8; ++ni) acc_s[mi][ni] = (floatx4){0.f, 0.f, 0.f, 0.f};
#pragma unroll
    for (int kc = 0; kc < 4; ++kc) {
#pragma unroll
      for (int ni = 0; ni < 8; ++ni) {
        int row = ni * 16 + l16;
        short8 b = *(const short8*)(&KVs[c][row * 128 + (((kc * 4 + qg) ^ (row & 7)) << 3)]);
        acc_s[0][ni] = __builtin_amdgcn_mfma_f32_16x16x32_bf16(aq[0][kc], b, acc_s[0][ni], 0, 0, 0);
        acc_s[1][ni] = __builtin_amdgcn_mfma_f32_16x16x32_bf16(aq[1][kc], b, acc_s[1][ni], 0, 0, 0);
      }
    }
    float alpha[2][4];
#pragma unroll
    for (int mi = 0; mi < 2; ++mi) {
#pragma unroll
      for (int r = 0; r < 4; ++r) {
        float mx = acc_s[mi][0][r];
#pragma unroll
        for (int ni = 1; ni < 8; ++ni) mx = fmaxf(mx, acc_s[mi][ni][r]);
        mx = fmaxf(mx, __shfl_xor(mx, 1));
        mx = fmaxf(mx, __shfl_xor(mx, 2));
        mx = fmaxf(mx, __shfl_xor(mx, 4));
        mx = fmaxf(mx, __shfl_xor(mx, 8));
        float mn = fmaxf(m_i[mi][r], mx);
        alpha[mi][r] = __expf(m_i[mi][r] - mn);
        m_i[mi][r] = mn;
      }
    }
#pragma unroll
    for (int mi = 0; mi < 2; ++mi) {
      float rs[4] = {0.f, 0.f, 0.f, 0.f};
#pragma unroll
      for (int ni = 0; ni < 8; ++ni) {
#pragma unroll
        for (int r = 0; r < 4; ++r) {
          float pv = __expf(acc_s[mi][ni][r] - m_i[mi][r]);
          rs[r] += pv;
          int row = w * 32 + mi * 16 + qg * 4 + r;
          int col = ni * 16 + l16;
          QPs[row * 128 + (((col >> 3) ^ (row & 7)) << 3) + (col & 7)] = f2b(pv);
        }
      }
#pragma unroll
      for (int r = 0; r < 4; ++r) {
        float t = rs[r];
        t += __shfl_xor(t, 1); t += __shfl_xor(t, 2);
        t += __shfl_xor(t, 4); t += __shfl_xor(t, 8);
        l_i[mi][r] = alpha[mi][r] * l_i[mi][r] + t;
      }
#pragma unroll
      for (int nd = 0; nd < 8; ++nd)
#pragma unroll
        for (int r = 0; r < 4; ++r) acc_o[mi][nd][r] *= alpha[mi][r];
    }
    asm volatile("s_waitcnt lgkmcnt(0)" ::: "memory");
    __builtin_amdgcn_s_barrier();
#pragma unroll
    for (int j = 0; j < 4; ++j) {
      int r = j * 32 + srow;
#pragma unroll
      for (int s = 0; s < 8; ++s) {
        int u = (s + sc) & 7;
        int d = sc * 8 + u;
        KVs[c][d * 128 + (((r >> 3) ^ (d & 7)) << 3) + (r & 7)] = vr[j][u];
      }
    }
    if (kt < 19) {
      const short* Vg = qkv + ((size_t)(kt + 1) * 128) * 9216 + 6144 + h * 128;
#pragma unroll
      for (int j = 0; j < 4; ++j) {
        int row = j * 32 + srow;
        vr[j] = *(const short8*)(Vg + (size_t)row * 9216 + sc * 8);
      }
    }
    asm volatile("s_waitcnt lgkmcnt(0)" ::: "memory");
    __builtin_amdgcn_s_barrier();
#pragma unroll
    for (int kc = 0; kc < 4; ++kc) {
      int prow0 = w * 32 + l16;
      short8 ap0 = *(const short8*)(QPs + prow0 * 128 + (((kc * 4 + qg) ^ (prow0 & 7)) << 3));
      int prow1 = prow0 + 16;
      short8 ap1 = *(const short8*)(QPs + prow1 * 128 + (((kc * 4 + qg) ^ (prow1 & 7)) << 3));
#pragma unroll
      for (int nd = 0; nd < 8; ++nd) {
        int row = nd * 16 + l16;
        short8 b = *(const short8*)(&KVs[c][row * 128 + (((kc * 4 + qg) ^ (row & 7)) << 3)]);
        acc_o[0][nd] = __builtin_amdgcn_mfma_f32_16x16x32_bf16(ap0, b, acc_o[0][nd], 0, 0, 0);
        acc_o[1][nd] = __builtin_amdgcn_mfma_f32_16x16x32_bf16(ap1, b, acc_o[1][nd], 0, 0, 0);
      }
    }
  }
#pragma unroll
  for (int mi = 0; mi < 2; ++mi) {
    float inv[4];
#pragma unroll
    for (int r = 0; r < 4; ++r) inv[r] = 1.0f / l_i[mi][r];
#pragma unroll
    for (int nd = 0; nd < 8; ++nd) {
#pragma unroll
      for (int r = 0; r < 4; ++r) {
        int row = q0 + w * 32 + mi * 16 + qg * 4 + r;
        int col = h * 128 + nd * 16 + l16;
        attn[(size_t)row * 3072 + col] = f2b(acc_o[mi][nd][r] * inv[r]);
      }
    }
  }
}

extern "C" void kernel_launch(void* const* d_in, const int* in_sizes, int n_in,
                              void* d_out, int out_size, void* d_ws, size_t ws_size,
                              hipStream_t stream) {
  (void)in_sizes; (void)n_in; (void)out_size;
  const void* hidden    = d_in[0];
  const void* enc       = d_in[1];
  const int*  ids       = (const int*)d_in[2];
  const void* w_qkv     = d_in[3];
  const void* w_add_qkv = d_in[4];
  const void* b_add_qkv = d_in[5];
  const void* w_out     = d_in[6];
  const void* b_out     = d_in[7];
  const void* w_add_out = d_in[8];
  const void* b_add_out = d_in[9];
  const void* nqw  = d_in[10];
  const void* nkw  = d_in[11];
  const void* naqw = d_in[12];
  const void* nakw = d_in[13];

  int*   dflag = (int*)d_ws;
  short* qkv   = (short*)((char*)d_ws + 256);   // [2560][9216] bf16 = 47,185,920 B
  short* attnB = qkv + (size_t)2560 * 9216;     // [2560][3072] bf16 = 15,728,640 B

  // bf16 pool (new path): hidden, enc, w_qkv, w_add_qkv, w_out, w_add_out
  short* pool  = attnB + (size_t)2560 * 3072;
  const long n_hid  = 2048L * 3072;     // 6,291,456
  const long n_enc  = 512L * 3072;      // 1,572,864
  const long n_wqkv = 3072L * 9216;     // 28,311,552
  const long n_wout = 3072L * 3072;     //  9,437,184
  short* hb   = pool;
  short* eb   = hb + n_hid;
  short* wqb  = eb + n_enc;
  short* waqb = wqb + n_wqkv;
  short* wob  = waqb + n_wqkv;
  short* waob = wob + n_wout;
  const size_t REQ = 256 + 2 * ((size_t)2560 * 9216 + (size_t)2560 * 3072 +
                                n_hid + n_enc + 2 * n_wqkv + 2 * n_wout);

  detect_dtype<<<1, 256, 0, stream>>>((const unsigned short*)w_qkv, dflag);

  if (ws_size >= REQ) {
    // ---- new path: one-time bf16 normalization, then pure-bf16 GEMMs
    cvt_bf16<<<2048, 256, 0, stream>>>(hidden,    hb,   n_hid  / 8, dflag);
    cvt_bf16<<<2048, 256, 0, stream>>>(enc,       eb,   n_enc  / 8, dflag);
    cvt_bf16<<<2048, 256, 0, stream>>>(w_qkv,     wqb,  n_wqkv / 8, dflag);
    cvt_bf16<<<2048, 256, 0, stream>>>(w_add_qkv, waqb, n_wqkv / 8, dflag);
    cvt_bf16<<<2048, 256, 0, stream>>>(w_out,     wob,  n_wout / 8, dflag);
    cvt_bf16<<<2048, 256, 0, stream>>>(w_add_out, waob, n_wout / 8, dflag);

    gemm_bf<<<dim3(72, 4), 256, 0, stream>>>(eb, 0, waqb, b_add_qkv, qkv, 0, 9216, 3072, dflag, 0);
    gemm_bf<<<dim3(72, 16), 256, 0, stream>>>(hb, 0, wqb, nullptr, qkv, 512, 9216, 3072, dflag, 0);
    norm_rope<<<dim3(2560, 24), 128, 0, stream>>>(qkv, ids, nqw, nkw, naqw, nakw, dflag);
    attn_fa<<<dim3(240), 512, 0, stream>>>(qkv, attnB);
    gemm_bf<<<dim3(24, 16), 256, 0, stream>>>(attnB, 512, wob, b_out, d_out, 0, 3072, 3072, dflag, 1);
    gemm_bf<<<dim3(24, 4), 256, 0, stream>>>(attnB, 0, waob, b_add_out, d_out, 2048, 3072, 3072, dflag, 1);
  } else {
    // ---- fallback: R2 path (workspace too small for bf16 pool)
    gemm_bt<<<dim3(72, 4), 256, 0, stream>>>(enc, 0, w_add_qkv, b_add_qkv, qkv, 0, 9216, 3072, dflag, 1, 0);
    gemm_bt<<<dim3(72, 16), 256, 0, stream>>>(hidden, 0, w_qkv, nullptr, qkv, 512, 9216, 3072, dflag, 1, 0);
    norm_rope<<<dim3(2560, 24), 128, 0, stream>>>(qkv, ids, nqw, nkw, naqw, nakw, dflag);
    attn_fa<<<dim3(240), 512, 0, stream>>>(qkv, attnB);
    gemm_bt<<<dim3(24, 16), 256, 0, stream>>>(attnB, 512, w_out, b_out, d_out, 0, 3072, 3072, dflag, 0, 1);
    gemm_bt<<<dim3(24, 4), 256, 0, stream>>>(attnB, 0, w_add_out, b_add_out, d_out, 2048, 3072, 3072, dflag, 0, 1);
  }
}

// Round 5
// 1371.912 us; speedup vs baseline: 1.7217x; 1.3186x over previous
//
#include <hip/hip_runtime.h>

typedef __attribute__((ext_vector_type(8))) short short8;
typedef __attribute__((ext_vector_type(4))) float floatx4;

__device__ __forceinline__ float b2f(short b) {
  union { unsigned u; float f; } v; v.u = ((unsigned)(unsigned short)b) << 16; return v.f;
}
__device__ __forceinline__ short f2b(float f) {
  union { float f; unsigned u; } v; v.f = f;
  return (short)((v.u + 0x7fffu + ((v.u >> 16) & 1u)) >> 16);
}
__device__ __forceinline__ float loadf(const void* p, size_t i, bool f32) {
  return f32 ? ((const float*)p)[i] : b2f(((const short*)p)[i]);
}
__device__ __forceinline__ short8 load8(const void* p, size_t i, bool f32) {
  if (f32) {
    const float* fp = (const float*)p + i;
    float4 a = *(const float4*)fp;
    float4 b = *(const float4*)(fp + 4);
    short8 r;
    r[0] = f2b(a.x); r[1] = f2b(a.y); r[2] = f2b(a.z); r[3] = f2b(a.w);
    r[4] = f2b(b.x); r[5] = f2b(b.y); r[6] = f2b(b.z); r[7] = f2b(b.w);
    return r;
  }
  return *(const short8*)((const short*)p + i);
}

// async global->LDS, 16B per lane. LDS dest = wave-uniform base + lane*16.
__device__ __forceinline__ void gload16(const short* g, short* l) {
  __builtin_amdgcn_global_load_lds(
      (const __attribute__((address_space(1))) unsigned int*)g,
      (__attribute__((address_space(3))) unsigned int*)l, 16, 0, 0);
}

// ---------- dtype detector: fp32 data read as shorts has random exponent fields
__global__ void detect_dtype(const unsigned short* __restrict__ w, int* __restrict__ flag) {
  __shared__ int cnt;
  if (threadIdx.x == 0) cnt = 0;
  __syncthreads();
  int bad = 0;
  for (int i = threadIdx.x; i < 4096; i += 256) {
    int e = (w[i] >> 7) & 0xFF;
    if (e >= 0xC8) bad++;  // |x| >= 2^73: impossible for real bf16 weights
  }
  atomicAdd(&cnt, bad);
  __syncthreads();
  if (threadIdx.x == 0) *flag = (cnt > 64) ? 1 : 0;
}

// ---------- one-time dtype normalization: src (fp32 or bf16, per dflag) -> bf16
__global__ __launch_bounds__(256)
void cvt_bf16(const void* __restrict__ src, short* __restrict__ dst, long n8,
              const int* __restrict__ dflag) {
  const bool f32 = (*dflag != 0);
  long stride = (long)gridDim.x * 256;
  for (long i = (long)blockIdx.x * 256 + threadIdx.x; i < n8; i += stride) {
    long e = i * 8;
    if (f32) {
      const float* fp = (const float*)src + e;
      float4 a = *(const float4*)fp;
      float4 b = *(const float4*)(fp + 4);
      short8 r;
      r[0] = f2b(a.x); r[1] = f2b(a.y); r[2] = f2b(a.z); r[3] = f2b(a.w);
      r[4] = f2b(b.x); r[5] = f2b(b.y); r[6] = f2b(b.z); r[7] = f2b(b.w);
      *(short8*)(dst + e) = r;
    } else {
      *(short8*)(dst + e) = *(const short8*)((const short*)src + e);
    }
  }
}

// ---------- OLD GEMM (fallback when workspace too small for bf16 pool) ----------
__global__ __launch_bounds__(256, 2)
void gemm_bt(const void* __restrict__ A, int a_row0,
             const void* __restrict__ B, const void* __restrict__ bias,
             void* __restrict__ C, int c_row0, int N, int K,
             const int* __restrict__ dflag, int aIn, int cOut) {
  __shared__ short As[128 * 32];
  __shared__ short Bs[128 * 32];
  const bool f32 = (*dflag != 0);
  const bool a32 = aIn && f32;
  const bool c32 = cOut && f32;
  const int tid = threadIdx.x;
  const int lane = tid & 63, w = tid >> 6;
  const int wm = w & 1, wn = w >> 1;
  const int qg = lane >> 4, l16 = lane & 15;
  const int m0 = blockIdx.y << 7, n0 = blockIdx.x << 7;

  const int arow = tid >> 2, ak = (tid & 3) << 3;
  const int brow = tid >> 4, bc = (tid & 15) << 3;
  const int rot = tid & 15;

  floatx4 acc[4][4];
#pragma unroll
  for (int i = 0; i < 4; ++i)
#pragma unroll
    for (int j = 0; j < 4; ++j) acc[i][j] = (floatx4){0.f, 0.f, 0.f, 0.f};

  for (int k0 = 0; k0 < K; k0 += 32) {
    __syncthreads();
#pragma unroll
    for (int j = 0; j < 2; ++j) {
      short8 av = load8(A, (size_t)(a_row0 + m0 + j * 64 + arow) * K + (k0 + ak), a32);
      *(short8*)(As + (j * 64 + arow) * 32 + ak) = av;
      int kr = j * 16 + brow;
      short8 bv = load8(B, (size_t)(k0 + kr) * N + (n0 + bc), f32);
      int kq = kr >> 3, kj = kr & 7;
#pragma unroll
      for (int s = 0; s < 8; ++s) {
        int u = (s + rot) & 7;
        int n = bc + u;
        Bs[(n << 5) + ((kq ^ (n & 3)) << 3) + kj] = bv[u];
      }
    }
    __syncthreads();
    short8 a[4];
#pragma unroll
    for (int mi = 0; mi < 4; ++mi)
      a[mi] = *(const short8*)(As + (wm * 64 + mi * 16 + l16) * 32 + qg * 8);
#pragma unroll
    for (int ni = 0; ni < 4; ++ni) {
      int n = wn * 64 + ni * 16 + l16;
      short8 b = *(const short8*)(Bs + (n << 5) + ((qg ^ (n & 3)) << 3));
#pragma unroll
      for (int mi = 0; mi < 4; ++mi)
        acc[mi][ni] = __builtin_amdgcn_mfma_f32_16x16x32_bf16(a[mi], b, acc[mi][ni], 0, 0, 0);
    }
  }
#pragma unroll
  for (int ni = 0; ni < 4; ++ni) {
    int col = n0 + wn * 64 + ni * 16 + l16;
    float bv = bias ? loadf(bias, col, f32) : 0.0f;
#pragma unroll
    for (int mi = 0; mi < 4; ++mi) {
      int row = m0 + wm * 64 + mi * 16 + qg * 4;
#pragma unroll
      for (int r = 0; r < 4; ++r) {
        size_t idx = (size_t)(c_row0 + row + r) * N + col;
        float val = acc[mi][ni][r] + bv;
        if (c32) ((float*)C)[idx] = val;
        else     ((short*)C)[idx] = f2b(val);
      }
    }
  }
}

// ---------- NEW GEMM: pure-bf16 A/B, double-buffered, global_load_lds A staging.
__global__ __launch_bounds__(256, 2)
void gemm_bf(const short* __restrict__ A, int a_row0,
             const short* __restrict__ B, const void* __restrict__ bias,
             void* __restrict__ C, int c_row0, int N, int K,
             const int* __restrict__ dflag, int cOut) {
  __shared__ short As[2][128 * 32];
  __shared__ short Bs[2][128 * 32];
  const bool f32 = (*dflag != 0);
  const bool c32 = cOut && f32;
  const int tid = threadIdx.x;
  const int lane = tid & 63, w = tid >> 6;
  const int wm = w & 1, wn = w >> 1;
  const int qg = lane >> 4, l16 = lane & 15;
  const int m0 = blockIdx.y << 7, n0 = blockIdx.x << 7;
  const int brow = tid >> 4, bc = (tid & 15) << 3;
  const int rot = tid & 15;
  const int garow = lane >> 2;   // gload: row within 16-row group
  const int gcir = lane & 3;     // gload: 16B chunk within row
  const int nk = K >> 5;

  floatx4 acc[4][4];
#pragma unroll
  for (int i = 0; i < 4; ++i)
#pragma unroll
    for (int j = 0; j < 4; ++j) acc[i][j] = (floatx4){0.f, 0.f, 0.f, 0.f};

  short8 bv0, bv1;
  // ---- prologue: stage tile 0 into buffer 0
  {
#pragma unroll
    for (int j = 0; j < 2; ++j) {
      int row = w * 32 + j * 16 + garow;
      gload16(A + (size_t)(a_row0 + m0 + row) * K + ((gcir ^ (row & 3)) << 3),
              &As[0][(w * 2 + j) << 9]);
    }
    bv0 = *(const short8*)(B + (size_t)(0 + brow) * N + (n0 + bc));
    bv1 = *(const short8*)(B + (size_t)(16 + brow) * N + (n0 + bc));
    asm volatile("s_waitcnt vmcnt(0)" ::: "memory");
#pragma unroll
    for (int j = 0; j < 2; ++j) {
      short8 bv = j ? bv1 : bv0;
      int kr = j * 16 + brow, kq = kr >> 3, kj = kr & 7;
#pragma unroll
      for (int s = 0; s < 8; ++s) {
        int u = (s + rot) & 7;
        int n = bc + u;
        Bs[0][(n << 5) + ((kq ^ (n & 3)) << 3) + kj] = bv[u];
      }
    }
    asm volatile("s_waitcnt lgkmcnt(0)" ::: "memory");
    __builtin_amdgcn_s_barrier();
  }

  for (int t = 0; t < nk; ++t) {
    const int c = t & 1;
    if (t + 1 < nk) {
      const int k0 = (t + 1) << 5;
#pragma unroll
      for (int j = 0; j < 2; ++j) {
        int row = w * 32 + j * 16 + garow;
        gload16(A + (size_t)(a_row0 + m0 + row) * K + k0 + ((gcir ^ (row & 3)) << 3),
                &As[1 - c][(w * 2 + j) << 9]);
      }
      bv0 = *(const short8*)(B + (size_t)(k0 + brow) * N + (n0 + bc));
      bv1 = *(const short8*)(B + (size_t)(k0 + 16 + brow) * N + (n0 + bc));
    }
    short8 a[4];
#pragma unroll
    for (int mi = 0; mi < 4; ++mi) {
      int ra = wm * 64 + mi * 16 + l16;
      a[mi] = *(const short8*)(&As[c][(ra << 5) + ((qg ^ (ra & 3)) << 3)]);
    }
#pragma unroll
    for (int ni = 0; ni < 4; ++ni) {
      int n = wn * 64 + ni * 16 + l16;
      short8 b = *(const short8*)(&Bs[c][(n << 5) + ((qg ^ (n & 3)) << 3)]);
#pragma unroll
      for (int mi = 0; mi < 4; ++mi)
        acc[mi][ni] = __builtin_amdgcn_mfma_f32_16x16x32_bf16(a[mi], b, acc[mi][ni], 0, 0, 0);
    }
    if (t + 1 < nk) {
      asm volatile("s_waitcnt vmcnt(0)" ::: "memory");
#pragma unroll
      for (int j = 0; j < 2; ++j) {
        short8 bv = j ? bv1 : bv0;
        int kr = j * 16 + brow, kq = kr >> 3, kj = kr & 7;
#pragma unroll
        for (int s = 0; s < 8; ++s) {
          int u = (s + rot) & 7;
          int n = bc + u;
          Bs[1 - c][(n << 5) + ((kq ^ (n & 3)) << 3) + kj] = bv[u];
        }
      }
      asm volatile("s_waitcnt lgkmcnt(0)" ::: "memory");
      __builtin_amdgcn_s_barrier();
    }
  }
#pragma unroll
  for (int ni = 0; ni < 4; ++ni) {
    int col = n0 + wn * 64 + ni * 16 + l16;
    float bvv = bias ? loadf(bias, col, f32) : 0.0f;
#pragma unroll
    for (int mi = 0; mi < 4; ++mi) {
      int row = m0 + wm * 64 + mi * 16 + qg * 4;
#pragma unroll
      for (int r = 0; r < 4; ++r) {
        size_t idx = (size_t)(c_row0 + row + r) * N + col;
        float val = acc[mi][ni][r] + bvv;
        if (c32) ((float*)C)[idx] = val;
        else     ((short*)C)[idx] = f2b(val);
      }
    }
  }
}

// ---------- in-place RMSNorm + RoPE on q,k inside qkv[t][9216]; 1/sqrt(128) folded into q
__global__ __launch_bounds__(128)
void norm_rope(short* __restrict__ qkv, const int* __restrict__ ids,
               const void* __restrict__ nqw, const void* __restrict__ nkw,
               const void* __restrict__ naqw, const void* __restrict__ nakw,
               const int* __restrict__ dflag) {
  const bool f32 = (*dflag != 0);
  const int t = blockIdx.x, h = blockIdx.y, d = threadIdx.x;
  const size_t base = (size_t)t * 9216 + h * 128 + d;
  float qv = b2f(qkv[base]);
  float kv = b2f(qkv[base + 3072]);
  float sq = qv * qv, sk = kv * kv;
#pragma unroll
  for (int o = 1; o < 64; o <<= 1) { sq += __shfl_xor(sq, o); sk += __shfl_xor(sk, o); }
  __shared__ float red[2][2];
  if ((d & 63) == 0) { red[0][d >> 6] = sq; red[1][d >> 6] = sk; }
  __syncthreads();
  sq = red[0][0] + red[0][1];
  sk = red[1][0] + red[1][1];
  float rq = rsqrtf(sq * (1.0f / 128.0f) + 1e-5f);
  float rk = rsqrtf(sk * (1.0f / 128.0f) + 1e-5f);
  const bool txt = t < 512;
  float qn = qv * rq * loadf(txt ? naqw : nqw, d, f32);
  float kn = kv * rk * loadf(txt ? nakw : nkw, d, f32);
  // rope axes (16,56,56): 8 + 28 + 28 freq pairs
  int p = d >> 1, axis; float expo;
  if (p < 8)       { axis = 0; expo = (float)(2 * p) * (1.0f / 16.0f); }
  else if (p < 36) { axis = 1; expo = (float)(2 * (p - 8)) * (1.0f / 56.0f); }
  else             { axis = 2; expo = (float)(2 * (p - 36)) * (1.0f / 56.0f); }
  float freq = __expf(-expo * 9.210340371976184f);  // 10000^-expo
  float ang = (float)ids[t * 3 + axis] * freq;
  float s, c; sincosf(ang, &s, &c);
  float qp = __shfl_xor(qn, 1), kp = __shfl_xor(kn, 1);
  float sgn = (d & 1) ? 1.0f : -1.0f;
  float qo = qn * c + sgn * qp * s;
  float ko = kn * c + sgn * kp * s;
  qkv[base]        = f2b(qo * 0.08838834764831845f);
  qkv[base + 3072] = f2b(ko);
}

// ---------- flash attention v5 (= v4 with fixed epilogue read-back indexing).
// Q-tile 256, K-tile 128. 8 waves (512 thr), wave w owns q-rows [32w,32w+32).
// k-order permutation t' = (t&15)*8 + (t>>4) applied to BOTH P's and V^T's LDS
// layouts (mfma only needs A/B to agree on k-order): P is stored as 8 packed
// ds_write_b128 per thread (was 64 scalar b16), full 16-slot XOR swizzle.
// Epilogue transposes through QPs (wave-private) then 8x coalesced b128 stores
// covering 4 rows x 16 chunks each (v4 bug: 8 rows x 8 chunks = half the cols).
__global__ __launch_bounds__(512, 2)
void attn_fa(const short* __restrict__ qkv, short* __restrict__ attn) {
  __shared__ short QPs[256 * 128];      // 64 KB
  __shared__ short KVs[2][128 * 128];   // 2 x 32 KB
  const int wgid = blockIdx.x;
  const int xcd = wgid & 7, slot = wgid >> 3;   // 30 slots/XCD
  const int h = xcd * 3 + slot / 10;            // 3 heads per XCD (L2-resident K/V)
  const int qt = slot % 10;
  const int tid = threadIdx.x, lane = tid & 63, w = tid >> 6;  // 8 waves
  const int qg = lane >> 4, l16 = lane & 15;
  const int lr = lane >> 4, lc = lane & 15;
  const int q0 = qt << 8;
  const int srow = tid >> 4, sc = tid & 15;

  const short* Qg  = qkv + (size_t)q0 * 9216 + h * 128;
  const short* Kg0 = qkv + 3072 + h * 128;
  const short* Vg0 = qkv + 6144 + h * 128;

  short8 vr[4];
#pragma unroll
  for (int j = 0; j < 8; ++j) {
    int row = j * 32 + w * 4 + lr;
    gload16(Qg + (size_t)row * 9216 + ((lc ^ (row & 7)) << 3),
            QPs + (j * 32 + w * 4) * 128);
  }
#pragma unroll
  for (int j = 0; j < 4; ++j) {
    int row = j * 32 + w * 4 + lr;
    gload16(Kg0 + (size_t)row * 9216 + ((lc ^ (row & 7)) << 3),
            &KVs[0][(j * 32 + w * 4) * 128]);
  }
#pragma unroll
  for (int j = 0; j < 4; ++j) {
    int row = j * 32 + srow;
    vr[j] = *(const short8*)(Vg0 + (size_t)row * 9216 + sc * 8);
  }
  asm volatile("s_waitcnt vmcnt(8) lgkmcnt(0)" ::: "memory");
  __builtin_amdgcn_s_barrier();
  short8 aq[2][4];
#pragma unroll
  for (int mi = 0; mi < 2; ++mi)
#pragma unroll
    for (int kc = 0; kc < 4; ++kc) {
      int row = w * 32 + mi * 16 + l16;
      aq[mi][kc] = *(const short8*)(QPs + row * 128 + (((kc * 4 + qg) ^ (row & 7)) << 3));
    }

  floatx4 acc_o[2][8];
#pragma unroll
  for (int mi = 0; mi < 2; ++mi)
#pragma unroll
    for (int nd = 0; nd < 8; ++nd) acc_o[mi][nd] = (floatx4){0.f, 0.f, 0.f, 0.f};
  float m_i[2][4], l_i[2][4];
#pragma unroll
  for (int mi = 0; mi < 2; ++mi)
#pragma unroll
    for (int r = 0; r < 4; ++r) { m_i[mi][r] = -1e30f; l_i[mi][r] = 0.0f; }

  for (int kt = 0; kt < 20; ++kt) {
    const int c = kt & 1;
    asm volatile("s_waitcnt vmcnt(4) lgkmcnt(0)" ::: "memory");
    __builtin_amdgcn_s_barrier();
    if (kt < 19) {
      const short* Kg = qkv + ((size_t)(kt + 1) * 128) * 9216 + 3072 + h * 128;
#pragma unroll
      for (int j = 0; j < 4; ++j) {
        int row = j * 32 + w * 4 + lr;
        gload16(Kg + (size_t)row * 9216 + ((lc ^ (row & 7)) << 3),
                &KVs[1 - c][(j * 32 + w * 4) * 128]);
      }
    }
    // ---- QK^T from KVs[c]
    floatx4 acc_s[2][8];
#pragma unroll
    for (int mi = 0; mi < 2; ++mi)
#pragma unroll
      for (int ni = 0; ni < 8; ++ni) acc_s[mi][ni] = (floatx4){0.f, 0.f, 0.f, 0.f};
    __builtin_amdgcn_s_setprio(1);
#pragma unroll
    for (int kc = 0; kc < 4; ++kc) {
#pragma unroll
      for (int ni = 0; ni < 8; ++ni) {
        int row = ni * 16 + l16;
        short8 b = *(const short8*)(&KVs[c][row * 128 + (((kc * 4 + qg) ^ (row & 7)) << 3)]);
        acc_s[0][ni] = __builtin_amdgcn_mfma_f32_16x16x32_bf16(aq[0][kc], b, acc_s[0][ni], 0, 0, 0);
        acc_s[1][ni] = __builtin_amdgcn_mfma_f32_16x16x32_bf16(aq[1][kc], b, acc_s[1][ni], 0, 0, 0);
      }
    }
    __builtin_amdgcn_s_setprio(0);
    // ---- online softmax (wave-private rows)
    float alpha[2][4];
#pragma unroll
    for (int mi = 0; mi < 2; ++mi) {
#pragma unroll
      for (int r = 0; r < 4; ++r) {
        float mx = acc_s[mi][0][r];
#pragma unroll
        for (int ni = 1; ni < 8; ++ni) mx = fmaxf(mx, acc_s[mi][ni][r]);
        mx = fmaxf(mx, __shfl_xor(mx, 1));
        mx = fmaxf(mx, __shfl_xor(mx, 2));
        mx = fmaxf(mx, __shfl_xor(mx, 4));
        mx = fmaxf(mx, __shfl_xor(mx, 8));
        float mn = fmaxf(m_i[mi][r], mx);
        alpha[mi][r] = __expf(m_i[mi][r] - mn);
        m_i[mi][r] = mn;
      }
    }
#pragma unroll
    for (int mi = 0; mi < 2; ++mi) {
      float rs[4] = {0.f, 0.f, 0.f, 0.f};
#pragma unroll
      for (int r = 0; r < 4; ++r) {
        // pack 8 P values (ni=0..7) -> one b128 store at permuted cols
        // t' = l16*8 + ni  (k-order permutation; V^T below uses the same)
        short8 p8;
#pragma unroll
        for (int ni = 0; ni < 8; ++ni) {
          float pv = __expf(acc_s[mi][ni][r] - m_i[mi][r]);
          rs[r] += pv;
          p8[ni] = f2b(pv);
        }
        int row = w * 32 + mi * 16 + qg * 4 + r;  // wave-private P row
        *(short8*)(QPs + row * 128 + ((l16 ^ (row & 15)) << 3)) = p8;
      }
#pragma unroll
      for (int r = 0; r < 4; ++r) {
        float t = rs[r];
        t += __shfl_xor(t, 1); t += __shfl_xor(t, 2);
        t += __shfl_xor(t, 4); t += __shfl_xor(t, 8);
        l_i[mi][r] = alpha[mi][r] * l_i[mi][r] + t;
      }
#pragma unroll
      for (int nd = 0; nd < 8; ++nd)
#pragma unroll
        for (int r = 0; r < 4; ++r) acc_o[mi][nd][r] *= alpha[mi][r];
    }
    asm volatile("s_waitcnt lgkmcnt(0)" ::: "memory");
    __builtin_amdgcn_s_barrier();
    // ---- commit V^T(kt) into KVs[c] with the SAME k-order permutation:
    // value for key token t goes to col t' where t'>>3 = t&15, t'&7 = t>>4.
#pragma unroll
    for (int j = 0; j < 4; ++j) {
      int r = j * 32 + srow;  // key token
#pragma unroll
      for (int s = 0; s < 8; ++s) {
        int u = (s + sc) & 7;
        int d = sc * 8 + u;
        KVs[c][d * 128 + (((r & 15) ^ (d & 7)) << 3) + (r >> 4)] = vr[j][u];
      }
    }
    if (kt < 19) {
      const short* Vg = qkv + ((size_t)(kt + 1) * 128) * 9216 + 6144 + h * 128;
#pragma unroll
      for (int j = 0; j < 4; ++j) {
        int row = j * 32 + srow;
        vr[j] = *(const short8*)(Vg + (size_t)row * 9216 + sc * 8);
      }
    }
    asm volatile("s_waitcnt lgkmcnt(0)" ::: "memory");
    __builtin_amdgcn_s_barrier();
    // ---- PV: A = P (chunk c at c^(row&15)), B = V^T (chunk c at c^(d&7)) —
    // k-orders match by construction.
    __builtin_amdgcn_s_setprio(1);
#pragma unroll
    for (int kc = 0; kc < 4; ++kc) {
      int prow0 = w * 32 + l16;
      short8 ap0 = *(const short8*)(QPs + prow0 * 128 + (((kc * 4 + qg) ^ (prow0 & 15)) << 3));
      int prow1 = prow0 + 16;
      short8 ap1 = *(const short8*)(QPs + prow1 * 128 + (((kc * 4 + qg) ^ (prow1 & 15)) << 3));
#pragma unroll
      for (int nd = 0; nd < 8; ++nd) {
        int row = nd * 16 + l16;
        short8 b = *(const short8*)(&KVs[c][row * 128 + (((kc * 4 + qg) ^ (row & 7)) << 3)]);
        acc_o[0][nd] = __builtin_amdgcn_mfma_f32_16x16x32_bf16(ap0, b, acc_o[0][nd], 0, 0, 0);
        acc_o[1][nd] = __builtin_amdgcn_mfma_f32_16x16x32_bf16(ap1, b, acc_o[1][nd], 0, 0, 0);
      }
    }
    __builtin_amdgcn_s_setprio(0);
  }
  // ---- epilogue: normalize, transpose through QPs (wave-private), b128 stores.
  // Write O[row][col] linear; read back 4 rows x 16 col-chunks per iteration.
#pragma unroll
  for (int mi = 0; mi < 2; ++mi) {
    float inv[4];
#pragma unroll
    for (int r = 0; r < 4; ++r) inv[r] = 1.0f / l_i[mi][r];
#pragma unroll
    for (int nd = 0; nd < 8; ++nd) {
#pragma unroll
      for (int r = 0; r < 4; ++r) {
        int row = w * 32 + mi * 16 + qg * 4 + r;
        QPs[row * 128 + nd * 16 + l16] = f2b(acc_o[mi][nd][r] * inv[r]);
      }
    }
  }
  asm volatile("s_waitcnt lgkmcnt(0)" ::: "memory");
#pragma unroll
  for (int j = 0; j < 8; ++j) {
    int rrow = w * 32 + j * 4 + qg;   // 4 rows x 16 col-chunks per iteration
    short8 vv = *(const short8*)(QPs + rrow * 128 + l16 * 8);
    *(short8*)(attn + (size_t)(q0 + rrow) * 3072 + h * 128 + l16 * 8) = vv;
  }
}

extern "C" void kernel_launch(void* const* d_in, const int* in_sizes, int n_in,
                              void* d_out, int out_size, void* d_ws, size_t ws_size,
                              hipStream_t stream) {
  (void)in_sizes; (void)n_in; (void)out_size;
  const void* hidden    = d_in[0];
  const void* enc       = d_in[1];
  const int*  ids       = (const int*)d_in[2];
  const void* w_qkv     = d_in[3];
  const void* w_add_qkv = d_in[4];
  const void* b_add_qkv = d_in[5];
  const void* w_out     = d_in[6];
  const void* b_out     = d_in[7];
  const void* w_add_out = d_in[8];
  const void* b_add_out = d_in[9];
  const void* nqw  = d_in[10];
  const void* nkw  = d_in[11];
  const void* naqw = d_in[12];
  const void* nakw = d_in[13];

  int*   dflag = (int*)d_ws;
  short* qkv   = (short*)((char*)d_ws + 256);   // [2560][9216] bf16 = 47,185,920 B
  short* attnB = qkv + (size_t)2560 * 9216;     // [2560][3072] bf16 = 15,728,640 B

  // bf16 pool (new path): hidden, enc, w_qkv, w_add_qkv, w_out, w_add_out
  short* pool  = attnB + (size_t)2560 * 3072;
  const long n_hid  = 2048L * 3072;
  const long n_enc  = 512L * 3072;
  const long n_wqkv = 3072L * 9216;
  const long n_wout = 3072L * 3072;
  short* hb   = pool;
  short* eb   = hb + n_hid;
  short* wqb  = eb + n_enc;
  short* waqb = wqb + n_wqkv;
  short* wob  = waqb + n_wqkv;
  short* waob = wob + n_wout;
  const size_t REQ = 256 + 2 * ((size_t)2560 * 9216 + (size_t)2560 * 3072 +
                                n_hid + n_enc + 2 * n_wqkv + 2 * n_wout);

  detect_dtype<<<1, 256, 0, stream>>>((const unsigned short*)w_qkv, dflag);

  if (ws_size >= REQ) {
    cvt_bf16<<<2048, 256, 0, stream>>>(hidden,    hb,   n_hid  / 8, dflag);
    cvt_bf16<<<2048, 256, 0, stream>>>(enc,       eb,   n_enc  / 8, dflag);
    cvt_bf16<<<2048, 256, 0, stream>>>(w_qkv,     wqb,  n_wqkv / 8, dflag);
    cvt_bf16<<<2048, 256, 0, stream>>>(w_add_qkv, waqb, n_wqkv / 8, dflag);
    cvt_bf16<<<2048, 256, 0, stream>>>(w_out,     wob,  n_wout / 8, dflag);
    cvt_bf16<<<2048, 256, 0, stream>>>(w_add_out, waob, n_wout / 8, dflag);

    gemm_bf<<<dim3(72, 4), 256, 0, stream>>>(eb, 0, waqb, b_add_qkv, qkv, 0, 9216, 3072, dflag, 0);
    gemm_bf<<<dim3(72, 16), 256, 0, stream>>>(hb, 0, wqb, nullptr, qkv, 512, 9216, 3072, dflag, 0);
    norm_rope<<<dim3(2560, 24), 128, 0, stream>>>(qkv, ids, nqw, nkw, naqw, nakw, dflag);
    attn_fa<<<dim3(240), 512, 0, stream>>>(qkv, attnB);
    gemm_bf<<<dim3(24, 16), 256, 0, stream>>>(attnB, 512, wob, b_out, d_out, 0, 3072, 3072, dflag, 1);
    gemm_bf<<<dim3(24, 4), 256, 0, stream>>>(attnB, 0, waob, b_add_out, d_out, 2048, 3072, 3072, dflag, 1);
  } else {
    gemm_bt<<<dim3(72, 4), 256, 0, stream>>>(enc, 0, w_add_qkv, b_add_qkv, qkv, 0, 9216, 3072, dflag, 1, 0);
    gemm_bt<<<dim3(72, 16), 256, 0, stream>>>(hidden, 0, w_qkv, nullptr, qkv, 512, 9216, 3072, dflag, 1, 0);
    norm_rope<<<dim3(2560, 24), 128, 0, stream>>>(qkv, ids, nqw, nkw, naqw, nakw, dflag);
    attn_fa<<<dim3(240), 512, 0, stream>>>(qkv, attnB);
    gemm_bt<<<dim3(24, 16), 256, 0, stream>>>(attnB, 512, w_out, b_out, d_out, 0, 3072, 3072, dflag, 0, 1);
    gemm_bt<<<dim3(24, 4), 256, 0, stream>>>(attnB, 0, w_add_out, b_add_out, d_out, 2048, 3072, 3072, dflag, 0, 1);
  }
}

// Round 6
// 1042.566 us; speedup vs baseline: 2.2656x; 1.3159x over previous
//
#include <hip/hip_runtime.h>

typedef __attribute__((ext_vector_type(8))) short short8;
typedef __attribute__((ext_vector_type(4))) float floatx4;

__device__ __forceinline__ float b2f(short b) {
  union { unsigned u; float f; } v; v.u = ((unsigned)(unsigned short)b) << 16; return v.f;
}
__device__ __forceinline__ short f2b(float f) {
  union { float f; unsigned u; } v; v.f = f;
  return (short)((v.u + 0x7fffu + ((v.u >> 16) & 1u)) >> 16);
}
__device__ __forceinline__ float loadf(const void* p, size_t i, bool f32) {
  return f32 ? ((const float*)p)[i] : b2f(((const short*)p)[i]);
}
__device__ __forceinline__ short8 load8(const void* p, size_t i, bool f32) {
  if (f32) {
    const float* fp = (const float*)p + i;
    float4 a = *(const float4*)fp;
    float4 b = *(const float4*)(fp + 4);
    short8 r;
    r[0] = f2b(a.x); r[1] = f2b(a.y); r[2] = f2b(a.z); r[3] = f2b(a.w);
    r[4] = f2b(b.x); r[5] = f2b(b.y); r[6] = f2b(b.z); r[7] = f2b(b.w);
    return r;
  }
  return *(const short8*)((const short*)p + i);
}

// async global->LDS, 16B per lane. LDS dest = wave-uniform base + lane*16.
__device__ __forceinline__ void gload16(const short* g, short* l) {
  __builtin_amdgcn_global_load_lds(
      (const __attribute__((address_space(1))) unsigned int*)g,
      (__attribute__((address_space(3))) unsigned int*)l, 16, 0, 0);
}

// ---------- dtype detector: fp32 data read as shorts has random exponent fields
__global__ void detect_dtype(const unsigned short* __restrict__ w, int* __restrict__ flag) {
  __shared__ int cnt;
  if (threadIdx.x == 0) cnt = 0;
  __syncthreads();
  int bad = 0;
  for (int i = threadIdx.x; i < 4096; i += 256) {
    int e = (w[i] >> 7) & 0xFF;
    if (e >= 0xC8) bad++;  // |x| >= 2^73: impossible for real bf16 weights
  }
  atomicAdd(&cnt, bad);
  __syncthreads();
  if (threadIdx.x == 0) *flag = (cnt > 64) ? 1 : 0;
}

// ---------- one-time dtype normalization: src (fp32 or bf16, per dflag) -> bf16
__global__ __launch_bounds__(256)
void cvt_bf16(const void* __restrict__ src, short* __restrict__ dst, long n8,
              const int* __restrict__ dflag) {
  const bool f32 = (*dflag != 0);
  long stride = (long)gridDim.x * 256;
  for (long i = (long)blockIdx.x * 256 + threadIdx.x; i < n8; i += stride) {
    long e = i * 8;
    if (f32) {
      const float* fp = (const float*)src + e;
      float4 a = *(const float4*)fp;
      float4 b = *(const float4*)(fp + 4);
      short8 r;
      r[0] = f2b(a.x); r[1] = f2b(a.y); r[2] = f2b(a.z); r[3] = f2b(a.w);
      r[4] = f2b(b.x); r[5] = f2b(b.y); r[6] = f2b(b.z); r[7] = f2b(b.w);
      *(short8*)(dst + e) = r;
    } else {
      *(short8*)(dst + e) = *(const short8*)((const short*)src + e);
    }
  }
}

// ---------- one-time transposing conversion: src [K][N] (dtype per dflag) -> dst [N][K] bf16.
// 64x64 tiles through padded LDS (stride 65 ints -> conflict-free both phases).
__global__ __launch_bounds__(256)
void cvt_t(const void* __restrict__ src, short* __restrict__ dst,
           int K, int N, const int* __restrict__ dflag) {
  __shared__ int tile[64][65];
  const bool f32 = (*dflag != 0);
  const int n0 = blockIdx.x << 6, k0 = blockIdx.y << 6;
  const int tx = threadIdx.x & 63, ty = threadIdx.x >> 6;
#pragma unroll
  for (int i = 0; i < 16; ++i) {
    int kl = i * 4 + ty;
    short v;
    if (f32) v = f2b(((const float*)src)[(size_t)(k0 + kl) * N + n0 + tx]);
    else     v = ((const short*)src)[(size_t)(k0 + kl) * N + n0 + tx];
    tile[tx][kl] = v;   // transposed store, lanes hit distinct banks (stride 65)
  }
  __syncthreads();
#pragma unroll
  for (int i = 0; i < 16; ++i) {
    int nl = i * 4 + ty;
    dst[(size_t)(n0 + nl) * K + k0 + tx] = (short)tile[nl][tx];
  }
}

// ---------- OLD GEMM (fallback when workspace too small for bf16 pool) ----------
__global__ __launch_bounds__(256, 2)
void gemm_bt(const void* __restrict__ A, int a_row0,
             const void* __restrict__ B, const void* __restrict__ bias,
             void* __restrict__ C, int c_row0, int N, int K,
             const int* __restrict__ dflag, int aIn, int cOut) {
  __shared__ short As[128 * 32];
  __shared__ short Bs[128 * 32];
  const bool f32 = (*dflag != 0);
  const bool a32 = aIn && f32;
  const bool c32 = cOut && f32;
  const int tid = threadIdx.x;
  const int lane = tid & 63, w = tid >> 6;
  const int wm = w & 1, wn = w >> 1;
  const int qg = lane >> 4, l16 = lane & 15;
  const int m0 = blockIdx.y << 7, n0 = blockIdx.x << 7;

  const int arow = tid >> 2, ak = (tid & 3) << 3;
  const int brow = tid >> 4, bc = (tid & 15) << 3;
  const int rot = tid & 15;

  floatx4 acc[4][4];
#pragma unroll
  for (int i = 0; i < 4; ++i)
#pragma unroll
    for (int j = 0; j < 4; ++j) acc[i][j] = (floatx4){0.f, 0.f, 0.f, 0.f};

  for (int k0 = 0; k0 < K; k0 += 32) {
    __syncthreads();
#pragma unroll
    for (int j = 0; j < 2; ++j) {
      short8 av = load8(A, (size_t)(a_row0 + m0 + j * 64 + arow) * K + (k0 + ak), a32);
      *(short8*)(As + (j * 64 + arow) * 32 + ak) = av;
      int kr = j * 16 + brow;
      short8 bv = load8(B, (size_t)(k0 + kr) * N + (n0 + bc), f32);
      int kq = kr >> 3, kj = kr & 7;
#pragma unroll
      for (int s = 0; s < 8; ++s) {
        int u = (s + rot) & 7;
        int n = bc + u;
        Bs[(n << 5) + ((kq ^ (n & 3)) << 3) + kj] = bv[u];
      }
    }
    __syncthreads();
    short8 a[4];
#pragma unroll
    for (int mi = 0; mi < 4; ++mi)
      a[mi] = *(const short8*)(As + (wm * 64 + mi * 16 + l16) * 32 + qg * 8);
#pragma unroll
    for (int ni = 0; ni < 4; ++ni) {
      int n = wn * 64 + ni * 16 + l16;
      short8 b = *(const short8*)(Bs + (n << 5) + ((qg ^ (n & 3)) << 3));
#pragma unroll
      for (int mi = 0; mi < 4; ++mi)
        acc[mi][ni] = __builtin_amdgcn_mfma_f32_16x16x32_bf16(a[mi], b, acc[mi][ni], 0, 0, 0);
    }
  }
#pragma unroll
  for (int ni = 0; ni < 4; ++ni) {
    int col = n0 + wn * 64 + ni * 16 + l16;
    float bv = bias ? loadf(bias, col, f32) : 0.0f;
#pragma unroll
    for (int mi = 0; mi < 4; ++mi) {
      int row = m0 + wm * 64 + mi * 16 + qg * 4;
#pragma unroll
      for (int r = 0; r < 4; ++r) {
        size_t idx = (size_t)(c_row0 + row + r) * N + col;
        float val = acc[mi][ni][r] + bv;
        if (c32) ((float*)C)[idx] = val;
        else     ((short*)C)[idx] = f2b(val);
      }
    }
  }
}

// ---------- GEMM v3: bf16 A [M][K] + pre-transposed bf16 B^T [N][K].
// Both operands staged via global_load_lds (linear dest + inverse-swizzled
// per-lane source, rule 21c), double-buffered, one vmcnt(0)+barrier per K-step.
// No reg-scatter: the 16 scalar ds_write_b16/thread and their VALU addr math
// (the 5.7e7 bank conflicts + 60% VALUBusy of R5) are gone.
// C[c_row0+.., N] = A[a_row0+.., K] @ B^T^T (+bias, dtype per dflag).
__global__ __launch_bounds__(256, 2)
void gemm_bf2(const short* __restrict__ A, int a_row0,
              const short* __restrict__ BT, const void* __restrict__ bias,
              void* __restrict__ C, int c_row0, int N, int K,
              const int* __restrict__ dflag, int cOut) {
  __shared__ short As[2][128 * 32];
  __shared__ short Bs[2][128 * 32];
  const bool f32 = (*dflag != 0);
  const bool c32 = cOut && f32;
  const int tid = threadIdx.x;
  const int lane = tid & 63, w = tid >> 6;
  const int wm = w & 1, wn = w >> 1;
  const int qg = lane >> 4, l16 = lane & 15;
  const int m0 = blockIdx.y << 7, n0 = blockIdx.x << 7;
  const int garow = lane >> 2;   // row within 16-row gload group
  const int gcir = lane & 3;     // 16B chunk within row
  const int nk = K >> 5;
  // row&3 == garow&3 for all staged rows (w*32 + j*16 both mult of 4)
  const int swz = (gcir ^ (garow & 3)) << 3;   // shorts
  const short* Abase = A + (size_t)(a_row0 + m0 + w * 32 + garow) * K + swz;
  const short* Bbase = BT + (size_t)(n0 + w * 32 + garow) * K + swz;

  floatx4 acc[4][4];
#pragma unroll
  for (int i = 0; i < 4; ++i)
#pragma unroll
    for (int j = 0; j < 4; ++j) acc[i][j] = (floatx4){0.f, 0.f, 0.f, 0.f};

  // prologue: stage tile 0 into buffer 0
#pragma unroll
  for (int j = 0; j < 2; ++j) {
    gload16(Abase + (size_t)j * 16 * K, &As[0][(w * 2 + j) << 9]);
    gload16(Bbase + (size_t)j * 16 * K, &Bs[0][(w * 2 + j) << 9]);
  }
  asm volatile("s_waitcnt vmcnt(0)" ::: "memory");
  __builtin_amdgcn_s_barrier();

  for (int t = 0; t < nk; ++t) {
    const int c = t & 1;
    if (t + 1 < nk) {
      const int k0 = (t + 1) << 5;
#pragma unroll
      for (int j = 0; j < 2; ++j) {
        gload16(Abase + (size_t)j * 16 * K + k0, &As[1 - c][(w * 2 + j) << 9]);
        gload16(Bbase + (size_t)j * 16 * K + k0, &Bs[1 - c][(w * 2 + j) << 9]);
      }
    }
    short8 a[4], b[4];
#pragma unroll
    for (int mi = 0; mi < 4; ++mi) {
      int ra = wm * 64 + mi * 16 + l16;
      a[mi] = *(const short8*)(&As[c][(ra << 5) + ((qg ^ (ra & 3)) << 3)]);
    }
#pragma unroll
    for (int ni = 0; ni < 4; ++ni) {
      int n = wn * 64 + ni * 16 + l16;
      b[ni] = *(const short8*)(&Bs[c][(n << 5) + ((qg ^ (n & 3)) << 3)]);
    }
    __builtin_amdgcn_s_setprio(1);
#pragma unroll
    for (int ni = 0; ni < 4; ++ni)
#pragma unroll
      for (int mi = 0; mi < 4; ++mi)
        acc[mi][ni] = __builtin_amdgcn_mfma_f32_16x16x32_bf16(a[mi], b[ni], acc[mi][ni], 0, 0, 0);
    __builtin_amdgcn_s_setprio(0);
    if (t + 1 < nk) {
      asm volatile("s_waitcnt vmcnt(0)" ::: "memory");
      __builtin_amdgcn_s_barrier();
    }
  }
  // epilogue
#pragma unroll
  for (int ni = 0; ni < 4; ++ni) {
    int col = n0 + wn * 64 + ni * 16 + l16;
    float bvv = bias ? loadf(bias, col, f32) : 0.0f;
#pragma unroll
    for (int mi = 0; mi < 4; ++mi) {
      int row = m0 + wm * 64 + mi * 16 + qg * 4;
#pragma unroll
      for (int r = 0; r < 4; ++r) {
        size_t idx = (size_t)(c_row0 + row + r) * N + col;
        float val = acc[mi][ni][r] + bvv;
        if (c32) ((float*)C)[idx] = val;
        else     ((short*)C)[idx] = f2b(val);
      }
    }
  }
}

// ---------- in-place RMSNorm + RoPE on q,k inside qkv[t][9216]; 1/sqrt(128) folded into q
__global__ __launch_bounds__(128)
void norm_rope(short* __restrict__ qkv, const int* __restrict__ ids,
               const void* __restrict__ nqw, const void* __restrict__ nkw,
               const void* __restrict__ naqw, const void* __restrict__ nakw,
               const int* __restrict__ dflag) {
  const bool f32 = (*dflag != 0);
  const int t = blockIdx.x, h = blockIdx.y, d = threadIdx.x;
  const size_t base = (size_t)t * 9216 + h * 128 + d;
  float qv = b2f(qkv[base]);
  float kv = b2f(qkv[base + 3072]);
  float sq = qv * qv, sk = kv * kv;
#pragma unroll
  for (int o = 1; o < 64; o <<= 1) { sq += __shfl_xor(sq, o); sk += __shfl_xor(sk, o); }
  __shared__ float red[2][2];
  if ((d & 63) == 0) { red[0][d >> 6] = sq; red[1][d >> 6] = sk; }
  __syncthreads();
  sq = red[0][0] + red[0][1];
  sk = red[1][0] + red[1][1];
  float rq = rsqrtf(sq * (1.0f / 128.0f) + 1e-5f);
  float rk = rsqrtf(sk * (1.0f / 128.0f) + 1e-5f);
  const bool txt = t < 512;
  float qn = qv * rq * loadf(txt ? naqw : nqw, d, f32);
  float kn = kv * rk * loadf(txt ? nakw : nkw, d, f32);
  // rope axes (16,56,56): 8 + 28 + 28 freq pairs
  int p = d >> 1, axis; float expo;
  if (p < 8)       { axis = 0; expo = (float)(2 * p) * (1.0f / 16.0f); }
  else if (p < 36) { axis = 1; expo = (float)(2 * (p - 8)) * (1.0f / 56.0f); }
  else             { axis = 2; expo = (float)(2 * (p - 36)) * (1.0f / 56.0f); }
  float freq = __expf(-expo * 9.210340371976184f);  // 10000^-expo
  float ang = (float)ids[t * 3 + axis] * freq;
  float s, c; sincosf(ang, &s, &c);
  float qp = __shfl_xor(qn, 1), kp = __shfl_xor(kn, 1);
  float sgn = (d & 1) ? 1.0f : -1.0f;
  float qo = qn * c + sgn * qp * s;
  float ko = kn * c + sgn * kp * s;
  qkv[base]        = f2b(qo * 0.08838834764831845f);
  qkv[base + 3072] = f2b(ko);
}

// ---------- flash attention v5 (unchanged from R5).
__global__ __launch_bounds__(512, 2)
void attn_fa(const short* __restrict__ qkv, short* __restrict__ attn) {
  __shared__ short QPs[256 * 128];      // 64 KB
  __shared__ short KVs[2][128 * 128];   // 2 x 32 KB
  const int wgid = blockIdx.x;
  const int xcd = wgid & 7, slot = wgid >> 3;   // 30 slots/XCD
  const int h = xcd * 3 + slot / 10;            // 3 heads per XCD (L2-resident K/V)
  const int qt = slot % 10;
  const int tid = threadIdx.x, lane = tid & 63, w = tid >> 6;  // 8 waves
  const int qg = lane >> 4, l16 = lane & 15;
  const int lr = lane >> 4, lc = lane & 15;
  const int q0 = qt << 8;
  const int srow = tid >> 4, sc = tid & 15;

  const short* Qg  = qkv + (size_t)q0 * 9216 + h * 128;
  const short* Kg0 = qkv + 3072 + h * 128;
  const short* Vg0 = qkv + 6144 + h * 128;

  short8 vr[4];
#pragma unroll
  for (int j = 0; j < 8; ++j) {
    int row = j * 32 + w * 4 + lr;
    gload16(Qg + (size_t)row * 9216 + ((lc ^ (row & 7)) << 3),
            QPs + (j * 32 + w * 4) * 128);
  }
#pragma unroll
  for (int j = 0; j < 4; ++j) {
    int row = j * 32 + w * 4 + lr;
    gload16(Kg0 + (size_t)row * 9216 + ((lc ^ (row & 7)) << 3),
            &KVs[0][(j * 32 + w * 4) * 128]);
  }
#pragma unroll
  for (int j = 0; j < 4; ++j) {
    int row = j * 32 + srow;
    vr[j] = *(const short8*)(Vg0 + (size_t)row * 9216 + sc * 8);
  }
  asm volatile("s_waitcnt vmcnt(8) lgkmcnt(0)" ::: "memory");
  __builtin_amdgcn_s_barrier();
  short8 aq[2][4];
#pragma unroll
  for (int mi = 0; mi < 2; ++mi)
#pragma unroll
    for (int kc = 0; kc < 4; ++kc) {
      int row = w * 32 + mi * 16 + l16;
      aq[mi][kc] = *(const short8*)(QPs + row * 128 + (((kc * 4 + qg) ^ (row & 7)) << 3));
    }

  floatx4 acc_o[2][8];
#pragma unroll
  for (int mi = 0; mi < 2; ++mi)
#pragma unroll
    for (int nd = 0; nd < 8; ++nd) acc_o[mi][nd] = (floatx4){0.f, 0.f, 0.f, 0.f};
  float m_i[2][4], l_i[2][4];
#pragma unroll
  for (int mi = 0; mi < 2; ++mi)
#pragma unroll
    for (int r = 0; r < 4; ++r) { m_i[mi][r] = -1e30f; l_i[mi][r] = 0.0f; }

  for (int kt = 0; kt < 20; ++kt) {
    const int c = kt & 1;
    asm volatile("s_waitcnt vmcnt(4) lgkmcnt(0)" ::: "memory");
    __builtin_amdgcn_s_barrier();
    if (kt < 19) {
      const short* Kg = qkv + ((size_t)(kt + 1) * 128) * 9216 + 3072 + h * 128;
#pragma unroll
      for (int j = 0; j < 4; ++j) {
        int row = j * 32 + w * 4 + lr;
        gload16(Kg + (size_t)row * 9216 + ((lc ^ (row & 7)) << 3),
                &KVs[1 - c][(j * 32 + w * 4) * 128]);
      }
    }
    // ---- QK^T from KVs[c]
    floatx4 acc_s[2][8];
#pragma unroll
    for (int mi = 0; mi < 2; ++mi)
#pragma unroll
      for (int ni = 0; ni < 8; ++ni) acc_s[mi][ni] = (floatx4){0.f, 0.f, 0.f, 0.f};
    __builtin_amdgcn_s_setprio(1);
#pragma unroll
    for (int kc = 0; kc < 4; ++kc) {
#pragma unroll
      for (int ni = 0; ni < 8; ++ni) {
        int row = ni * 16 + l16;
        short8 b = *(const short8*)(&KVs[c][row * 128 + (((kc * 4 + qg) ^ (row & 7)) << 3)]);
        acc_s[0][ni] = __builtin_amdgcn_mfma_f32_16x16x32_bf16(aq[0][kc], b, acc_s[0][ni], 0, 0, 0);
        acc_s[1][ni] = __builtin_amdgcn_mfma_f32_16x16x32_bf16(aq[1][kc], b, acc_s[1][ni], 0, 0, 0);
      }
    }
    __builtin_amdgcn_s_setprio(0);
    // ---- online softmax (wave-private rows)
    float alpha[2][4];
#pragma unroll
    for (int mi = 0; mi < 2; ++mi) {
#pragma unroll
      for (int r = 0; r < 4; ++r) {
        float mx = acc_s[mi][0][r];
#pragma unroll
        for (int ni = 1; ni < 8; ++ni) mx = fmaxf(mx, acc_s[mi][ni][r]);
        mx = fmaxf(mx, __shfl_xor(mx, 1));
        mx = fmaxf(mx, __shfl_xor(mx, 2));
        mx = fmaxf(mx, __shfl_xor(mx, 4));
        mx = fmaxf(mx, __shfl_xor(mx, 8));
        float mn = fmaxf(m_i[mi][r], mx);
        alpha[mi][r] = __expf(m_i[mi][r] - mn);
        m_i[mi][r] = mn;
      }
    }
#pragma unroll
    for (int mi = 0; mi < 2; ++mi) {
      float rs[4] = {0.f, 0.f, 0.f, 0.f};
#pragma unroll
      for (int r = 0; r < 4; ++r) {
        short8 p8;
#pragma unroll
        for (int ni = 0; ni < 8; ++ni) {
          float pv = __expf(acc_s[mi][ni][r] - m_i[mi][r]);
          rs[r] += pv;
          p8[ni] = f2b(pv);
        }
        int row = w * 32 + mi * 16 + qg * 4 + r;  // wave-private P row
        *(short8*)(QPs + row * 128 + ((l16 ^ (row & 15)) << 3)) = p8;
      }
#pragma unroll
      for (int r = 0; r < 4; ++r) {
        float t = rs[r];
        t += __shfl_xor(t, 1); t += __shfl_xor(t, 2);
        t += __shfl_xor(t, 4); t += __shfl_xor(t, 8);
        l_i[mi][r] = alpha[mi][r] * l_i[mi][r] + t;
      }
#pragma unroll
      for (int nd = 0; nd < 8; ++nd)
#pragma unroll
        for (int r = 0; r < 4; ++r) acc_o[mi][nd][r] *= alpha[mi][r];
    }
    asm volatile("s_waitcnt lgkmcnt(0)" ::: "memory");
    __builtin_amdgcn_s_barrier();
    // ---- commit V^T(kt) into KVs[c] with the k-order permutation
#pragma unroll
    for (int j = 0; j < 4; ++j) {
      int r = j * 32 + srow;  // key token
#pragma unroll
      for (int s = 0; s < 8; ++s) {
        int u = (s + sc) & 7;
        int d = sc * 8 + u;
        KVs[c][d * 128 + (((r & 15) ^ (d & 7)) << 3) + (r >> 4)] = vr[j][u];
      }
    }
    if (kt < 19) {
      const short* Vg = qkv + ((size_t)(kt + 1) * 128) * 9216 + 6144 + h * 128;
#pragma unroll
      for (int j = 0; j < 4; ++j) {
        int row = j * 32 + srow;
        vr[j] = *(const short8*)(Vg + (size_t)row * 9216 + sc * 8);
      }
    }
    asm volatile("s_waitcnt lgkmcnt(0)" ::: "memory");
    __builtin_amdgcn_s_barrier();
    // ---- PV
    __builtin_amdgcn_s_setprio(1);
#pragma unroll
    for (int kc = 0; kc < 4; ++kc) {
      int prow0 = w * 32 + l16;
      short8 ap0 = *(const short8*)(QPs + prow0 * 128 + (((kc * 4 + qg) ^ (prow0 & 15)) << 3));
      int prow1 = prow0 + 16;
      short8 ap1 = *(const short8*)(QPs + prow1 * 128 + (((kc * 4 + qg) ^ (prow1 & 15)) << 3));
#pragma unroll
      for (int nd = 0; nd < 8; ++nd) {
        int row = nd * 16 + l16;
        short8 b = *(const short8*)(&KVs[c][row * 128 + (((kc * 4 + qg) ^ (row & 7)) << 3)]);
        acc_o[0][nd] = __builtin_amdgcn_mfma_f32_16x16x32_bf16(ap0, b, acc_o[0][nd], 0, 0, 0);
        acc_o[1][nd] = __builtin_amdgcn_mfma_f32_16x16x32_bf16(ap1, b, acc_o[1][nd], 0, 0, 0);
      }
    }
    __builtin_amdgcn_s_setprio(0);
  }
  // ---- epilogue: normalize, transpose through QPs, coalesced b128 stores
#pragma unroll
  for (int mi = 0; mi < 2; ++mi) {
    float inv[4];
#pragma unroll
    for (int r = 0; r < 4; ++r) inv[r] = 1.0f / l_i[mi][r];
#pragma unroll
    for (int nd = 0; nd < 8; ++nd) {
#pragma unroll
      for (int r = 0; r < 4; ++r) {
        int row = w * 32 + mi * 16 + qg * 4 + r;
        QPs[row * 128 + nd * 16 + l16] = f2b(acc_o[mi][nd][r] * inv[r]);
      }
    }
  }
  asm volatile("s_waitcnt lgkmcnt(0)" ::: "memory");
#pragma unroll
  for (int j = 0; j < 8; ++j) {
    int rrow = w * 32 + j * 4 + qg;   // 4 rows x 16 col-chunks per iteration
    short8 vv = *(const short8*)(QPs + rrow * 128 + l16 * 8);
    *(short8*)(attn + (size_t)(q0 + rrow) * 3072 + h * 128 + l16 * 8) = vv;
  }
}

extern "C" void kernel_launch(void* const* d_in, const int* in_sizes, int n_in,
                              void* d_out, int out_size, void* d_ws, size_t ws_size,
                              hipStream_t stream) {
  (void)in_sizes; (void)n_in; (void)out_size;
  const void* hidden    = d_in[0];
  const void* enc       = d_in[1];
  const int*  ids       = (const int*)d_in[2];
  const void* w_qkv     = d_in[3];
  const void* w_add_qkv = d_in[4];
  const void* b_add_qkv = d_in[5];
  const void* w_out     = d_in[6];
  const void* b_out     = d_in[7];
  const void* w_add_out = d_in[8];
  const void* b_add_out = d_in[9];
  const void* nqw  = d_in[10];
  const void* nkw  = d_in[11];
  const void* naqw = d_in[12];
  const void* nakw = d_in[13];

  int*   dflag = (int*)d_ws;
  short* qkv   = (short*)((char*)d_ws + 256);   // [2560][9216] bf16
  short* attnB = qkv + (size_t)2560 * 9216;     // [2560][3072] bf16

  // bf16 pool: hidden, enc (row-major) + w_qkv^T, w_add_qkv^T, w_out^T, w_add_out^T
  short* pool  = attnB + (size_t)2560 * 3072;
  const long n_hid  = 2048L * 3072;
  const long n_enc  = 512L * 3072;
  const long n_wqkv = 3072L * 9216;
  const long n_wout = 3072L * 3072;
  short* hb   = pool;
  short* eb   = hb + n_hid;
  short* wqb  = eb + n_enc;        // w_qkv^T    [9216][3072]
  short* waqb = wqb + n_wqkv;      // w_add_qkv^T[9216][3072]
  short* wob  = waqb + n_wqkv;     // w_out^T    [3072][3072]
  short* waob = wob + n_wout;      // w_add_out^T[3072][3072]
  const size_t REQ = 256 + 2 * ((size_t)2560 * 9216 + (size_t)2560 * 3072 +
                                n_hid + n_enc + 2 * n_wqkv + 2 * n_wout);

  detect_dtype<<<1, 256, 0, stream>>>((const unsigned short*)w_qkv, dflag);

  if (ws_size >= REQ) {
    cvt_bf16<<<1024, 256, 0, stream>>>(hidden, hb, n_hid / 8, dflag);
    cvt_bf16<<<256, 256, 0, stream>>>(enc, eb, n_enc / 8, dflag);
    cvt_t<<<dim3(144, 48), 256, 0, stream>>>(w_qkv,     wqb,  3072, 9216, dflag);
    cvt_t<<<dim3(144, 48), 256, 0, stream>>>(w_add_qkv, waqb, 3072, 9216, dflag);
    cvt_t<<<dim3(48, 48), 256, 0, stream>>>(w_out,     wob,  3072, 3072, dflag);
    cvt_t<<<dim3(48, 48), 256, 0, stream>>>(w_add_out, waob, 3072, 3072, dflag);

    gemm_bf2<<<dim3(72, 4), 256, 0, stream>>>(eb, 0, waqb, b_add_qkv, qkv, 0, 9216, 3072, dflag, 0);
    gemm_bf2<<<dim3(72, 16), 256, 0, stream>>>(hb, 0, wqb, nullptr, qkv, 512, 9216, 3072, dflag, 0);
    norm_rope<<<dim3(2560, 24), 128, 0, stream>>>(qkv, ids, nqw, nkw, naqw, nakw, dflag);
    attn_fa<<<dim3(240), 512, 0, stream>>>(qkv, attnB);
    gemm_bf2<<<dim3(24, 16), 256, 0, stream>>>(attnB, 512, wob, b_out, d_out, 0, 3072, 3072, dflag, 1);
    gemm_bf2<<<dim3(24, 4), 256, 0, stream>>>(attnB, 0, waob, b_add_out, d_out, 2048, 3072, 3072, dflag, 1);
  } else {
    gemm_bt<<<dim3(72, 4), 256, 0, stream>>>(enc, 0, w_add_qkv, b_add_qkv, qkv, 0, 9216, 3072, dflag, 1, 0);
    gemm_bt<<<dim3(72, 16), 256, 0, stream>>>(hidden, 0, w_qkv, nullptr, qkv, 512, 9216, 3072, dflag, 1, 0);
    norm_rope<<<dim3(2560, 24), 128, 0, stream>>>(qkv, ids, nqw, nkw, naqw, nakw, dflag);
    attn_fa<<<dim3(240), 512, 0, stream>>>(qkv, attnB);
    gemm_bt<<<dim3(24, 16), 256, 0, stream>>>(attnB, 512, w_out, b_out, d_out, 0, 3072, 3072, dflag, 0, 1);
    gemm_bt<<<dim3(24, 4), 256, 0, stream>>>(attnB, 0, w_add_out, b_add_out, d_out, 2048, 3072, 3072, dflag, 0, 1);
  }
}

// Round 7
// 1030.046 us; speedup vs baseline: 2.2931x; 1.0122x over previous
//
#include <hip/hip_runtime.h>

typedef __attribute__((ext_vector_type(8))) short short8;
typedef __attribute__((ext_vector_type(4))) float floatx4;

__device__ __forceinline__ float b2f(short b) {
  union { unsigned u; float f; } v; v.u = ((unsigned)(unsigned short)b) << 16; return v.f;
}
__device__ __forceinline__ short f2b(float f) {
  union { float f; unsigned u; } v; v.f = f;
  return (short)((v.u + 0x7fffu + ((v.u >> 16) & 1u)) >> 16);
}
__device__ __forceinline__ float loadf(const void* p, size_t i, bool f32) {
  return f32 ? ((const float*)p)[i] : b2f(((const short*)p)[i]);
}
__device__ __forceinline__ short8 load8(const void* p, size_t i, bool f32) {
  if (f32) {
    const float* fp = (const float*)p + i;
    float4 a = *(const float4*)fp;
    float4 b = *(const float4*)(fp + 4);
    short8 r;
    r[0] = f2b(a.x); r[1] = f2b(a.y); r[2] = f2b(a.z); r[3] = f2b(a.w);
    r[4] = f2b(b.x); r[5] = f2b(b.y); r[6] = f2b(b.z); r[7] = f2b(b.w);
    return r;
  }
  return *(const short8*)((const short*)p + i);
}

// async global->LDS, 16B per lane. LDS dest = wave-uniform base + lane*16.
__device__ __forceinline__ void gload16(const short* g, short* l) {
  __builtin_amdgcn_global_load_lds(
      (const __attribute__((address_space(1))) unsigned int*)g,
      (__attribute__((address_space(3))) unsigned int*)l, 16, 0, 0);
}

// ---------- dtype detector: fp32 data read as shorts has random exponent fields
__global__ void detect_dtype(const unsigned short* __restrict__ w, int* __restrict__ flag) {
  __shared__ int cnt;
  if (threadIdx.x == 0) cnt = 0;
  __syncthreads();
  int bad = 0;
  for (int i = threadIdx.x; i < 4096; i += 256) {
    int e = (w[i] >> 7) & 0xFF;
    if (e >= 0xC8) bad++;  // |x| >= 2^73: impossible for real bf16 weights
  }
  atomicAdd(&cnt, bad);
  __syncthreads();
  if (threadIdx.x == 0) *flag = (cnt > 64) ? 1 : 0;
}

// ---------- one-time dtype normalization: src (fp32 or bf16, per dflag) -> bf16
__global__ __launch_bounds__(256)
void cvt_bf16(const void* __restrict__ src, short* __restrict__ dst, long n8,
              const int* __restrict__ dflag) {
  const bool f32 = (*dflag != 0);
  long stride = (long)gridDim.x * 256;
  for (long i = (long)blockIdx.x * 256 + threadIdx.x; i < n8; i += stride) {
    long e = i * 8;
    if (f32) {
      const float* fp = (const float*)src + e;
      float4 a = *(const float4*)fp;
      float4 b = *(const float4*)(fp + 4);
      short8 r;
      r[0] = f2b(a.x); r[1] = f2b(a.y); r[2] = f2b(a.z); r[3] = f2b(a.w);
      r[4] = f2b(b.x); r[5] = f2b(b.y); r[6] = f2b(b.z); r[7] = f2b(b.w);
      *(short8*)(dst + e) = r;
    } else {
      *(short8*)(dst + e) = *(const short8*)((const short*)src + e);
    }
  }
}

// ---------- one-time transposing conversion: src [K][N] (dtype per dflag) -> dst [N][K] bf16.
__global__ __launch_bounds__(256)
void cvt_t(const void* __restrict__ src, short* __restrict__ dst,
           int K, int N, const int* __restrict__ dflag) {
  __shared__ int tile[64][65];
  const bool f32 = (*dflag != 0);
  const int n0 = blockIdx.x << 6, k0 = blockIdx.y << 6;
  const int tx = threadIdx.x & 63, ty = threadIdx.x >> 6;
#pragma unroll
  for (int i = 0; i < 16; ++i) {
    int kl = i * 4 + ty;
    short v;
    if (f32) v = f2b(((const float*)src)[(size_t)(k0 + kl) * N + n0 + tx]);
    else     v = ((const short*)src)[(size_t)(k0 + kl) * N + n0 + tx];
    tile[tx][kl] = v;   // transposed store, lanes hit distinct banks (stride 65)
  }
  __syncthreads();
#pragma unroll
  for (int i = 0; i < 16; ++i) {
    int nl = i * 4 + ty;
    dst[(size_t)(n0 + nl) * K + k0 + tx] = (short)tile[nl][tx];
  }
}

// ---------- OLD GEMM (fallback when workspace too small for bf16 pool) ----------
__global__ __launch_bounds__(256, 2)
void gemm_bt(const void* __restrict__ A, int a_row0,
             const void* __restrict__ B, const void* __restrict__ bias,
             void* __restrict__ C, int c_row0, int N, int K,
             const int* __restrict__ dflag, int aIn, int cOut) {
  __shared__ short As[128 * 32];
  __shared__ short Bs[128 * 32];
  const bool f32 = (*dflag != 0);
  const bool a32 = aIn && f32;
  const bool c32 = cOut && f32;
  const int tid = threadIdx.x;
  const int lane = tid & 63, w = tid >> 6;
  const int wm = w & 1, wn = w >> 1;
  const int qg = lane >> 4, l16 = lane & 15;
  const int m0 = blockIdx.y << 7, n0 = blockIdx.x << 7;

  const int arow = tid >> 2, ak = (tid & 3) << 3;
  const int brow = tid >> 4, bc = (tid & 15) << 3;
  const int rot = tid & 15;

  floatx4 acc[4][4];
#pragma unroll
  for (int i = 0; i < 4; ++i)
#pragma unroll
    for (int j = 0; j < 4; ++j) acc[i][j] = (floatx4){0.f, 0.f, 0.f, 0.f};

  for (int k0 = 0; k0 < K; k0 += 32) {
    __syncthreads();
#pragma unroll
    for (int j = 0; j < 2; ++j) {
      short8 av = load8(A, (size_t)(a_row0 + m0 + j * 64 + arow) * K + (k0 + ak), a32);
      *(short8*)(As + (j * 64 + arow) * 32 + ak) = av;
      int kr = j * 16 + brow;
      short8 bv = load8(B, (size_t)(k0 + kr) * N + (n0 + bc), f32);
      int kq = kr >> 3, kj = kr & 7;
#pragma unroll
      for (int s = 0; s < 8; ++s) {
        int u = (s + rot) & 7;
        int n = bc + u;
        Bs[(n << 5) + ((kq ^ (n & 3)) << 3) + kj] = bv[u];
      }
    }
    __syncthreads();
    short8 a[4];
#pragma unroll
    for (int mi = 0; mi < 4; ++mi)
      a[mi] = *(const short8*)(As + (wm * 64 + mi * 16 + l16) * 32 + qg * 8);
#pragma unroll
    for (int ni = 0; ni < 4; ++ni) {
      int n = wn * 64 + ni * 16 + l16;
      short8 b = *(const short8*)(Bs + (n << 5) + ((qg ^ (n & 3)) << 3));
#pragma unroll
      for (int mi = 0; mi < 4; ++mi)
        acc[mi][ni] = __builtin_amdgcn_mfma_f32_16x16x32_bf16(a[mi], b, acc[mi][ni], 0, 0, 0);
    }
  }
#pragma unroll
  for (int ni = 0; ni < 4; ++ni) {
    int col = n0 + wn * 64 + ni * 16 + l16;
    float bv = bias ? loadf(bias, col, f32) : 0.0f;
#pragma unroll
    for (int mi = 0; mi < 4; ++mi) {
      int row = m0 + wm * 64 + mi * 16 + qg * 4;
#pragma unroll
      for (int r = 0; r < 4; ++r) {
        size_t idx = (size_t)(c_row0 + row + r) * N + col;
        float val = acc[mi][ni][r] + bv;
        if (c32) ((float*)C)[idx] = val;
        else     ((short*)C)[idx] = f2b(val);
      }
    }
  }
}

// ---------- GEMM v4: bf16 A [M][K] + pre-transposed bf16 B^T [N][K].
// Both staged via global_load_lds, double-buffered, one vmcnt(0)+barrier per step.
// Swizzle v2: chunk_phys = chunk_log ^ (row&3) ^ ((row>>2)&3).
// R6 evidence: with only ^(row&3), a b128-read phase (16 lanes, qg fixed) had
// bank-group 16*(row&1)+4*chunk -> rows {0,4,8,12} collide = 4-way conflict
// (1.42e7/dispatch). Folding (row>>2)&3 in makes 8 groups x 2 rows = 2-way (free).
__global__ __launch_bounds__(256, 2)
void gemm_bf2(const short* __restrict__ A, int a_row0,
              const short* __restrict__ BT, const void* __restrict__ bias,
              void* __restrict__ C, int c_row0, int N, int K,
              const int* __restrict__ dflag, int cOut) {
  __shared__ short As[2][128 * 32];
  __shared__ short Bs[2][128 * 32];
  const bool f32 = (*dflag != 0);
  const bool c32 = cOut && f32;
  const int tid = threadIdx.x;
  const int lane = tid & 63, w = tid >> 6;
  const int wm = w & 1, wn = w >> 1;
  const int qg = lane >> 4, l16 = lane & 15;
  const int m0 = blockIdx.y << 7, n0 = blockIdx.x << 7;
  const int garow = lane >> 2;   // row within 16-row gload group
  const int gcir = lane & 3;     // 16B chunk within row
  const int nk = K >> 5;
  // source pre-swizzle must match the read swizzle: ^(row&3)^((row>>2)&3).
  // For staged rows w*32+j*16+garow: row&3 = garow&3, (row>>2)&3 = garow>>2.
  const int swz = (gcir ^ (garow & 3) ^ (garow >> 2)) << 3;   // shorts
  const short* Abase = A + (size_t)(a_row0 + m0 + w * 32 + garow) * K + swz;
  const short* Bbase = BT + (size_t)(n0 + w * 32 + garow) * K + swz;
  // read-side chunk xor: for ra = 64*wm + 16*mi + l16, (ra&3)^((ra>>2)&3)
  // reduces to (l16&3)^(l16>>2) (mi*16, wm*64 are 0 mod 16).
  const int rswz = (l16 & 3) ^ (l16 >> 2);

  floatx4 acc[4][4];
#pragma unroll
  for (int i = 0; i < 4; ++i)
#pragma unroll
    for (int j = 0; j < 4; ++j) acc[i][j] = (floatx4){0.f, 0.f, 0.f, 0.f};

  // prologue: stage tile 0 into buffer 0
#pragma unroll
  for (int j = 0; j < 2; ++j) {
    gload16(Abase + (size_t)j * 16 * K, &As[0][(w * 2 + j) << 9]);
    gload16(Bbase + (size_t)j * 16 * K, &Bs[0][(w * 2 + j) << 9]);
  }
  asm volatile("s_waitcnt vmcnt(0)" ::: "memory");
  __builtin_amdgcn_s_barrier();

  for (int t = 0; t < nk; ++t) {
    const int c = t & 1;
    if (t + 1 < nk) {
      const int k0 = (t + 1) << 5;
#pragma unroll
      for (int j = 0; j < 2; ++j) {
        gload16(Abase + (size_t)j * 16 * K + k0, &As[1 - c][(w * 2 + j) << 9]);
        gload16(Bbase + (size_t)j * 16 * K + k0, &Bs[1 - c][(w * 2 + j) << 9]);
      }
    }
    short8 a[4], b[4];
#pragma unroll
    for (int mi = 0; mi < 4; ++mi) {
      int ra = wm * 64 + mi * 16 + l16;
      a[mi] = *(const short8*)(&As[c][(ra << 5) + ((qg ^ rswz) << 3)]);
    }
#pragma unroll
    for (int ni = 0; ni < 4; ++ni) {
      int n = wn * 64 + ni * 16 + l16;
      b[ni] = *(const short8*)(&Bs[c][(n << 5) + ((qg ^ rswz) << 3)]);
    }
    __builtin_amdgcn_s_setprio(1);
#pragma unroll
    for (int ni = 0; ni < 4; ++ni)
#pragma unroll
      for (int mi = 0; mi < 4; ++mi)
        acc[mi][ni] = __builtin_amdgcn_mfma_f32_16x16x32_bf16(a[mi], b[ni], acc[mi][ni], 0, 0, 0);
    __builtin_amdgcn_s_setprio(0);
    if (t + 1 < nk) {
      asm volatile("s_waitcnt vmcnt(0)" ::: "memory");
      __builtin_amdgcn_s_barrier();
    }
  }
  // epilogue
#pragma unroll
  for (int ni = 0; ni < 4; ++ni) {
    int col = n0 + wn * 64 + ni * 16 + l16;
    float bvv = bias ? loadf(bias, col, f32) : 0.0f;
#pragma unroll
    for (int mi = 0; mi < 4; ++mi) {
      int row = m0 + wm * 64 + mi * 16 + qg * 4;
#pragma unroll
      for (int r = 0; r < 4; ++r) {
        size_t idx = (size_t)(c_row0 + row + r) * N + col;
        float val = acc[mi][ni][r] + bvv;
        if (c32) ((float*)C)[idx] = val;
        else     ((short*)C)[idx] = f2b(val);
      }
    }
  }
}

// ---------- RMSNorm + RoPE v2: one wave per head, lane owns the RoPE pair
// (d = 2*lane, 2*lane+1) -> rope needs NO shuffle; RMS reduce is wave-local.
// No LDS, no __syncthreads. 2560 blocks x 512 thr (8 waves, 3 heads each) vs
// R6's 61440 x 128 launch-bound version.
__global__ __launch_bounds__(512)
void norm_rope(short* __restrict__ qkv, const int* __restrict__ ids,
               const void* __restrict__ nqw, const void* __restrict__ nkw,
               const void* __restrict__ naqw, const void* __restrict__ nakw,
               const int* __restrict__ dflag) {
  const bool f32 = (*dflag != 0);
  const int t = blockIdx.x, wv = threadIdx.x >> 6, lane = threadIdx.x & 63;
  const bool txt = t < 512;
  // rope angle for pair p = lane (same for all heads of this token)
  int p = lane, axis; float expo;
  if (p < 8)       { axis = 0; expo = (float)(2 * p) * (1.0f / 16.0f); }
  else if (p < 36) { axis = 1; expo = (float)(2 * (p - 8)) * (1.0f / 56.0f); }
  else             { axis = 2; expo = (float)(2 * (p - 36)) * (1.0f / 56.0f); }
  float freq = __expf(-expo * 9.210340371976184f);  // 10000^-expo
  float ang = (float)ids[t * 3 + axis] * freq;
  float s, c; sincosf(ang, &s, &c);
  const void* qw = txt ? naqw : nqw;
  const void* kw = txt ? nakw : nkw;
  float w0q = loadf(qw, 2 * lane, f32), w1q = loadf(qw, 2 * lane + 1, f32);
  float w0k = loadf(kw, 2 * lane, f32), w1k = loadf(kw, 2 * lane + 1, f32);
#pragma unroll
  for (int i = 0; i < 3; ++i) {
    int h = wv + 8 * i;
    short* qp = qkv + (size_t)t * 9216 + h * 128 + 2 * lane;
    short* kp = qp + 3072;
    union { unsigned u; short sh[2]; } qv, kv;
    qv.u = *(const unsigned*)qp;
    kv.u = *(const unsigned*)kp;
    float q0 = b2f(qv.sh[0]), q1 = b2f(qv.sh[1]);
    float k0 = b2f(kv.sh[0]), k1 = b2f(kv.sh[1]);
    float sq = q0 * q0 + q1 * q1, sk = k0 * k0 + k1 * k1;
#pragma unroll
    for (int o = 1; o < 64; o <<= 1) { sq += __shfl_xor(sq, o); sk += __shfl_xor(sk, o); }
    float rq = rsqrtf(sq * (1.0f / 128.0f) + 1e-5f);
    float rk = rsqrtf(sk * (1.0f / 128.0f) + 1e-5f);
    float qn0 = q0 * rq * w0q, qn1 = q1 * rq * w1q;
    float kn0 = k0 * rk * w0k, kn1 = k1 * rk * w1k;
    float qo0 = qn0 * c - qn1 * s, qo1 = qn1 * c + qn0 * s;
    float ko0 = kn0 * c - kn1 * s, ko1 = kn1 * c + kn0 * s;
    union { unsigned u; short sh[2]; } qo, ko;
    qo.sh[0] = f2b(qo0 * 0.08838834764831845f);
    qo.sh[1] = f2b(qo1 * 0.08838834764831845f);
    ko.sh[0] = f2b(ko0); ko.sh[1] = f2b(ko1);
    *(unsigned*)qp = qo.u;
    *(unsigned*)kp = ko.u;
  }
}

// ---------- flash attention v5 (unchanged from R6).
__global__ __launch_bounds__(512, 2)
void attn_fa(const short* __restrict__ qkv, short* __restrict__ attn) {
  __shared__ short QPs[256 * 128];      // 64 KB
  __shared__ short KVs[2][128 * 128];   // 2 x 32 KB
  const int wgid = blockIdx.x;
  const int xcd = wgid & 7, slot = wgid >> 3;   // 30 slots/XCD
  const int h = xcd * 3 + slot / 10;            // 3 heads per XCD (L2-resident K/V)
  const int qt = slot % 10;
  const int tid = threadIdx.x, lane = tid & 63, w = tid >> 6;  // 8 waves
  const int qg = lane >> 4, l16 = lane & 15;
  const int lr = lane >> 4, lc = lane & 15;
  const int q0 = qt << 8;
  const int srow = tid >> 4, sc = tid & 15;

  const short* Qg  = qkv + (size_t)q0 * 9216 + h * 128;
  const short* Kg0 = qkv + 3072 + h * 128;
  const short* Vg0 = qkv + 6144 + h * 128;

  short8 vr[4];
#pragma unroll
  for (int j = 0; j < 8; ++j) {
    int row = j * 32 + w * 4 + lr;
    gload16(Qg + (size_t)row * 9216 + ((lc ^ (row & 7)) << 3),
            QPs + (j * 32 + w * 4) * 128);
  }
#pragma unroll
  for (int j = 0; j < 4; ++j) {
    int row = j * 32 + w * 4 + lr;
    gload16(Kg0 + (size_t)row * 9216 + ((lc ^ (row & 7)) << 3),
            &KVs[0][(j * 32 + w * 4) * 128]);
  }
#pragma unroll
  for (int j = 0; j < 4; ++j) {
    int row = j * 32 + srow;
    vr[j] = *(const short8*)(Vg0 + (size_t)row * 9216 + sc * 8);
  }
  asm volatile("s_waitcnt vmcnt(8) lgkmcnt(0)" ::: "memory");
  __builtin_amdgcn_s_barrier();
  short8 aq[2][4];
#pragma unroll
  for (int mi = 0; mi < 2; ++mi)
#pragma unroll
    for (int kc = 0; kc < 4; ++kc) {
      int row = w * 32 + mi * 16 + l16;
      aq[mi][kc] = *(const short8*)(QPs + row * 128 + (((kc * 4 + qg) ^ (row & 7)) << 3));
    }

  floatx4 acc_o[2][8];
#pragma unroll
  for (int mi = 0; mi < 2; ++mi)
#pragma unroll
    for (int nd = 0; nd < 8; ++nd) acc_o[mi][nd] = (floatx4){0.f, 0.f, 0.f, 0.f};
  float m_i[2][4], l_i[2][4];
#pragma unroll
  for (int mi = 0; mi < 2; ++mi)
#pragma unroll
    for (int r = 0; r < 4; ++r) { m_i[mi][r] = -1e30f; l_i[mi][r] = 0.0f; }

  for (int kt = 0; kt < 20; ++kt) {
    const int c = kt & 1;
    asm volatile("s_waitcnt vmcnt(4) lgkmcnt(0)" ::: "memory");
    __builtin_amdgcn_s_barrier();
    if (kt < 19) {
      const short* Kg = qkv + ((size_t)(kt + 1) * 128) * 9216 + 3072 + h * 128;
#pragma unroll
      for (int j = 0; j < 4; ++j) {
        int row = j * 32 + w * 4 + lr;
        gload16(Kg + (size_t)row * 9216 + ((lc ^ (row & 7)) << 3),
                &KVs[1 - c][(j * 32 + w * 4) * 128]);
      }
    }
    // ---- QK^T from KVs[c]
    floatx4 acc_s[2][8];
#pragma unroll
    for (int mi = 0; mi < 2; ++mi)
#pragma unroll
      for (int ni = 0; ni < 8; ++ni) acc_s[mi][ni] = (floatx4){0.f, 0.f, 0.f, 0.f};
    __builtin_amdgcn_s_setprio(1);
#pragma unroll
    for (int kc = 0; kc < 4; ++kc) {
#pragma unroll
      for (int ni = 0; ni < 8; ++ni) {
        int row = ni * 16 + l16;
        short8 b = *(const short8*)(&KVs[c][row * 128 + (((kc * 4 + qg) ^ (row & 7)) << 3)]);
        acc_s[0][ni] = __builtin_amdgcn_mfma_f32_16x16x32_bf16(aq[0][kc], b, acc_s[0][ni], 0, 0, 0);
        acc_s[1][ni] = __builtin_amdgcn_mfma_f32_16x16x32_bf16(aq[1][kc], b, acc_s[1][ni], 0, 0, 0);
      }
    }
    __builtin_amdgcn_s_setprio(0);
    // ---- online softmax (wave-private rows)
    float alpha[2][4];
#pragma unroll
    for (int mi = 0; mi < 2; ++mi) {
#pragma unroll
      for (int r = 0; r < 4; ++r) {
        float mx = acc_s[mi][0][r];
#pragma unroll
        for (int ni = 1; ni < 8; ++ni) mx = fmaxf(mx, acc_s[mi][ni][r]);
        mx = fmaxf(mx, __shfl_xor(mx, 1));
        mx = fmaxf(mx, __shfl_xor(mx, 2));
        mx = fmaxf(mx, __shfl_xor(mx, 4));
        mx = fmaxf(mx, __shfl_xor(mx, 8));
        float mn = fmaxf(m_i[mi][r], mx);
        alpha[mi][r] = __expf(m_i[mi][r] - mn);
        m_i[mi][r] = mn;
      }
    }
#pragma unroll
    for (int mi = 0; mi < 2; ++mi) {
      float rs[4] = {0.f, 0.f, 0.f, 0.f};
#pragma unroll
      for (int r = 0; r < 4; ++r) {
        short8 p8;
#pragma unroll
        for (int ni = 0; ni < 8; ++ni) {
          float pv = __expf(acc_s[mi][ni][r] - m_i[mi][r]);
          rs[r] += pv;
          p8[ni] = f2b(pv);
        }
        int row = w * 32 + mi * 16 + qg * 4 + r;  // wave-private P row
        *(short8*)(QPs + row * 128 + ((l16 ^ (row & 15)) << 3)) = p8;
      }
#pragma unroll
      for (int r = 0; r < 4; ++r) {
        float t = rs[r];
        t += __shfl_xor(t, 1); t += __shfl_xor(t, 2);
        t += __shfl_xor(t, 4); t += __shfl_xor(t, 8);
        l_i[mi][r] = alpha[mi][r] * l_i[mi][r] + t;
      }
#pragma unroll
      for (int nd = 0; nd < 8; ++nd)
#pragma unroll
        for (int r = 0; r < 4; ++r) acc_o[mi][nd][r] *= alpha[mi][r];
    }
    asm volatile("s_waitcnt lgkmcnt(0)" ::: "memory");
    __builtin_amdgcn_s_barrier();
    // ---- commit V^T(kt) into KVs[c] with the k-order permutation
#pragma unroll
    for (int j = 0; j < 4; ++j) {
      int r = j * 32 + srow;  // key token
#pragma unroll
      for (int s = 0; s < 8; ++s) {
        int u = (s + sc) & 7;
        int d = sc * 8 + u;
        KVs[c][d * 128 + (((r & 15) ^ (d & 7)) << 3) + (r >> 4)] = vr[j][u];
      }
    }
    if (kt < 19) {
      const short* Vg = qkv + ((size_t)(kt + 1) * 128) * 9216 + 6144 + h * 128;
#pragma unroll
      for (int j = 0; j < 4; ++j) {
        int row = j * 32 + srow;
        vr[j] = *(const short8*)(Vg + (size_t)row * 9216 + sc * 8);
      }
    }
    asm volatile("s_waitcnt lgkmcnt(0)" ::: "memory");
    __builtin_amdgcn_s_barrier();
    // ---- PV
    __builtin_amdgcn_s_setprio(1);
#pragma unroll
    for (int kc = 0; kc < 4; ++kc) {
      int prow0 = w * 32 + l16;
      short8 ap0 = *(const short8*)(QPs + prow0 * 128 + (((kc * 4 + qg) ^ (prow0 & 15)) << 3));
      int prow1 = prow0 + 16;
      short8 ap1 = *(const short8*)(QPs + prow1 * 128 + (((kc * 4 + qg) ^ (prow1 & 15)) << 3));
#pragma unroll
      for (int nd = 0; nd < 8; ++nd) {
        int row = nd * 16 + l16;
        short8 b = *(const short8*)(&KVs[c][row * 128 + (((kc * 4 + qg) ^ (row & 7)) << 3)]);
        acc_o[0][nd] = __builtin_amdgcn_mfma_f32_16x16x32_bf16(ap0, b, acc_o[0][nd], 0, 0, 0);
        acc_o[1][nd] = __builtin_amdgcn_mfma_f32_16x16x32_bf16(ap1, b, acc_o[1][nd], 0, 0, 0);
      }
    }
    __builtin_amdgcn_s_setprio(0);
  }
  // ---- epilogue: normalize, transpose through QPs, coalesced b128 stores
#pragma unroll
  for (int mi = 0; mi < 2; ++mi) {
    float inv[4];
#pragma unroll
    for (int r = 0; r < 4; ++r) inv[r] = 1.0f / l_i[mi][r];
#pragma unroll
    for (int nd = 0; nd < 8; ++nd) {
#pragma unroll
      for (int r = 0; r < 4; ++r) {
        int row = w * 32 + mi * 16 + qg * 4 + r;
        QPs[row * 128 + nd * 16 + l16] = f2b(acc_o[mi][nd][r] * inv[r]);
      }
    }
  }
  asm volatile("s_waitcnt lgkmcnt(0)" ::: "memory");
#pragma unroll
  for (int j = 0; j < 8; ++j) {
    int rrow = w * 32 + j * 4 + qg;   // 4 rows x 16 col-chunks per iteration
    short8 vv = *(const short8*)(QPs + rrow * 128 + l16 * 8);
    *(short8*)(attn + (size_t)(q0 + rrow) * 3072 + h * 128 + l16 * 8) = vv;
  }
}

extern "C" void kernel_launch(void* const* d_in, const int* in_sizes, int n_in,
                              void* d_out, int out_size, void* d_ws, size_t ws_size,
                              hipStream_t stream) {
  (void)in_sizes; (void)n_in; (void)out_size;
  const void* hidden    = d_in[0];
  const void* enc       = d_in[1];
  const int*  ids       = (const int*)d_in[2];
  const void* w_qkv     = d_in[3];
  const void* w_add_qkv = d_in[4];
  const void* b_add_qkv = d_in[5];
  const void* w_out     = d_in[6];
  const void* b_out     = d_in[7];
  const void* w_add_out = d_in[8];
  const void* b_add_out = d_in[9];
  const void* nqw  = d_in[10];
  const void* nkw  = d_in[11];
  const void* naqw = d_in[12];
  const void* nakw = d_in[13];

  int*   dflag = (int*)d_ws;
  short* qkv   = (short*)((char*)d_ws + 256);   // [2560][9216] bf16
  short* attnB = qkv + (size_t)2560 * 9216;     // [2560][3072] bf16

  // bf16 pool: hidden, enc (row-major) + w_qkv^T, w_add_qkv^T, w_out^T, w_add_out^T
  short* pool  = attnB + (size_t)2560 * 3072;
  const long n_hid  = 2048L * 3072;
  const long n_enc  = 512L * 3072;
  const long n_wqkv = 3072L * 9216;
  const long n_wout = 3072L * 3072;
  short* hb   = pool;
  short* eb   = hb + n_hid;
  short* wqb  = eb + n_enc;        // w_qkv^T    [9216][3072]
  short* waqb = wqb + n_wqkv;      // w_add_qkv^T[9216][3072]
  short* wob  = waqb + n_wqkv;     // w_out^T    [3072][3072]
  short* waob = wob + n_wout;      // w_add_out^T[3072][3072]
  const size_t REQ = 256 + 2 * ((size_t)2560 * 9216 + (size_t)2560 * 3072 +
                                n_hid + n_enc + 2 * n_wqkv + 2 * n_wout);

  detect_dtype<<<1, 256, 0, stream>>>((const unsigned short*)w_qkv, dflag);

  if (ws_size >= REQ) {
    cvt_bf16<<<1024, 256, 0, stream>>>(hidden, hb, n_hid / 8, dflag);
    cvt_bf16<<<256, 256, 0, stream>>>(enc, eb, n_enc / 8, dflag);
    cvt_t<<<dim3(144, 48), 256, 0, stream>>>(w_qkv,     wqb,  3072, 9216, dflag);
    cvt_t<<<dim3(144, 48), 256, 0, stream>>>(w_add_qkv, waqb, 3072, 9216, dflag);
    cvt_t<<<dim3(48, 48), 256, 0, stream>>>(w_out,     wob,  3072, 3072, dflag);
    cvt_t<<<dim3(48, 48), 256, 0, stream>>>(w_add_out, waob, 3072, 3072, dflag);

    gemm_bf2<<<dim3(72, 4), 256, 0, stream>>>(eb, 0, waqb, b_add_qkv, qkv, 0, 9216, 3072, dflag, 0);
    gemm_bf2<<<dim3(72, 16), 256, 0, stream>>>(hb, 0, wqb, nullptr, qkv, 512, 9216, 3072, dflag, 0);
    norm_rope<<<dim3(2560), 512, 0, stream>>>(qkv, ids, nqw, nkw, naqw, nakw, dflag);
    attn_fa<<<dim3(240), 512, 0, stream>>>(qkv, attnB);
    gemm_bf2<<<dim3(24, 16), 256, 0, stream>>>(attnB, 512, wob, b_out, d_out, 0, 3072, 3072, dflag, 1);
    gemm_bf2<<<dim3(24, 4), 256, 0, stream>>>(attnB, 0, waob, b_add_out, d_out, 2048, 3072, 3072, dflag, 1);
  } else {
    gemm_bt<<<dim3(72, 4), 256, 0, stream>>>(enc, 0, w_add_qkv, b_add_qkv, qkv, 0, 9216, 3072, dflag, 1, 0);
    gemm_bt<<<dim3(72, 16), 256, 0, stream>>>(hidden, 0, w_qkv, nullptr, qkv, 512, 9216, 3072, dflag, 1, 0);
    norm_rope<<<dim3(2560), 512, 0, stream>>>(qkv, ids, nqw, nkw, naqw, nakw, dflag);
    attn_fa<<<dim3(240), 512, 0, stream>>>(qkv, attnB);
    gemm_bt<<<dim3(24, 16), 256, 0, stream>>>(attnB, 512, w_out, b_out, d_out, 0, 3072, 3072, dflag, 0, 1);
    gemm_bt<<<dim3(24, 4), 256, 0, stream>>>(attnB, 0, w_add_out, b_add_out, d_out, 2048, 3072, 3072, dflag, 0, 1);
  }
}